// Round 9
// baseline (658.749 us; speedup 1.0000x reference)
//
#include <hip/hip_runtime.h>
#include <type_traits>

// ---------------------------------------------------------------------------
// RelationalTransformer: B=32 T=4 L=1024 D=1024 H=8 Hd=128 N=15
// out = edge_logits (32*15*15*18 = 129600) ++ energy (32)   [fp32]
//
// R9 = exact R5 source (bfgemm v1, the 512us best) + INSTRUMENTATION:
// 3 extra replica launches of each bfgemm call (idempotent rewrites of the
// same workspace buffers). dur_us = base + 3*(bfgemm pair) -> resolves the
// 10x disagreement between cycle-model (~25us pair) and subtraction
// accounting (~280us pair). absmax must stay exactly 6.103516e-05.
// ---------------------------------------------------------------------------

typedef __attribute__((ext_vector_type(8))) short bf16x8;   // 8 bf16 in 4 VGPRs
typedef __attribute__((ext_vector_type(4))) float f32x4;

__device__ __forceinline__ unsigned short f2bf(float f) {   // RNE float->bf16
    unsigned int u = __float_as_uint(f);
    u = u + 0x7FFFu + ((u >> 16) & 1u);
    return (unsigned short)(u >> 16);
}

// ---------------- generic strided-batched fp32 GEMM:  C = alpha*A@op(B) + bias
template <int BM, int BN, int BK, int TM, int TN, bool BT, bool OUTBF = false>
__global__ __launch_bounds__(256) void gemm_k(
    const float* __restrict__ A, const float* __restrict__ B,
    const float* __restrict__ bias, void* __restrict__ Cv,
    int M, int N, int K, int lda, int ldb, int ldc,
    long sA1, long sB1, long sC1, long sb1,
    int batch2, long sA2, long sB2, long sC2, long sb2,
    float alpha)
{
    using OutT = typename std::conditional<OUTBF, unsigned short, float>::type;
    const int z  = blockIdx.z;
    const int z1 = z / batch2, z2 = z % batch2;
    A += z1 * sA1 + z2 * sA2;
    B += z1 * sB1 + z2 * sB2;
    OutT* C = ((OutT*)Cv) + z1 * sC1 + z2 * sC2;
    const float* bp = bias ? (bias + z1 * sb1 + z2 * sb2) : nullptr;

    const int m0 = blockIdx.y * BM;
    const int n0 = blockIdx.x * BN;

    __shared__ float As[BK * BM];
    __shared__ float Bs[BK * BN];

    const int t   = threadIdx.x;
    const int TNW = BN / TN;
    const int tn  = t % TNW;
    const int tm  = t / TNW;

    float acc[TM][TN];
#pragma unroll
    for (int i = 0; i < TM; ++i)
#pragma unroll
        for (int j = 0; j < TN; ++j) acc[i][j] = 0.0f;

    for (int k0 = 0; k0 < K; k0 += BK) {
        constexpr int ACH = BM * BK / 4;
        for (int c = t; c < ACH; c += 256) {
            const int flat = c * 4;
            const int kq = flat % BK, m = flat / BK;
            float4 v = make_float4(0.f, 0.f, 0.f, 0.f);
            if (m0 + m < M)
                v = *(const float4*)&A[(long)(m0 + m) * lda + k0 + kq];
            As[(kq + 0) * BM + m] = v.x;
            As[(kq + 1) * BM + m] = v.y;
            As[(kq + 2) * BM + m] = v.z;
            As[(kq + 3) * BM + m] = v.w;
        }
        constexpr int BCH = BN * BK / 4;
        if constexpr (BT) {
            for (int c = t; c < BCH; c += 256) {
                const int flat = c * 4;
                const int kq = flat % BK, n = flat / BK;
                float4 v = *(const float4*)&B[(long)(n0 + n) * ldb + k0 + kq];
                Bs[(kq + 0) * BN + n] = v.x;
                Bs[(kq + 1) * BN + n] = v.y;
                Bs[(kq + 2) * BN + n] = v.z;
                Bs[(kq + 3) * BN + n] = v.w;
            }
        } else {
            for (int c = t; c < BCH; c += 256) {
                const int flat = c * 4;
                const int n = flat % BN, kq = flat / BN;
                float4 v = *(const float4*)&B[(long)(k0 + kq) * ldb + n0 + n];
                *(float4*)&Bs[kq * BN + n] = v;
            }
        }
        __syncthreads();

#pragma unroll
        for (int kk = 0; kk < BK; ++kk) {
            float a[TM], bvv[TN];
            if constexpr (TM == 4) {
                float4 v = *(const float4*)&As[kk * BM + tm * 4];
                a[0] = v.x; a[1] = v.y; a[2] = v.z; a[3] = v.w;
            } else {
#pragma unroll
                for (int i = 0; i < TM; ++i) a[i] = As[kk * BM + tm * TM + i];
            }
            if constexpr (TN == 4) {
                float4 v = *(const float4*)&Bs[kk * BN + tn * 4];
                bvv[0] = v.x; bvv[1] = v.y; bvv[2] = v.z; bvv[3] = v.w;
            } else {
#pragma unroll
                for (int j = 0; j < TN; ++j) bvv[j] = Bs[kk * BN + tn * TN + j];
            }
#pragma unroll
            for (int i = 0; i < TM; ++i)
#pragma unroll
                for (int j = 0; j < TN; ++j) acc[i][j] += a[i] * bvv[j];
        }
        __syncthreads();
    }

#pragma unroll
    for (int i = 0; i < TM; ++i) {
        const int m = m0 + tm * TM + i;
        if (m >= M) continue;
#pragma unroll
        for (int j = 0; j < TN; ++j) {
            const int n = n0 + tn * TN + j;
            float v = acc[i][j] * alpha;
            if (bp) v += bp[n];
            if constexpr (OUTBF)
                C[(long)m * ldc + n] = f2bf(v);
            else
                C[(long)m * ldc + n] = v;
        }
    }
}

// ---------------- bf16 MFMA GEMM v1: C[m][n] = sum_k A[m][k]*B[n][k]
// Tile 64x128, 4 waves (2x2). (R5 best-known version, verbatim.)
__global__ __launch_bounds__(256) void bfgemm_k(
    const unsigned short* __restrict__ A, const unsigned short* __restrict__ B,
    float* __restrict__ C, int M, long sA, long sB, long sC)
{
    const int b  = blockIdx.z;
    const int m0 = blockIdx.y * 64;
    const int n0 = blockIdx.x * 128;
    const unsigned short* Ab = A + b * sA;
    const unsigned short* Bb = B + b * sB;
    float* Cb = C + b * sC;

    __shared__ __align__(16) unsigned short As[64 * 32];   // [m][k]
    __shared__ __align__(16) unsigned short Bs[128 * 32];  // [n][k]

    const int t    = threadIdx.x;
    const int lane = t & 63;
    const int w    = t >> 6;
    const int wm   = w >> 1, wn = w & 1;       // wave tile: 32 x 64

    f32x4 acc[2][4] = {};

    const int ar = t >> 2;              // staging row (0..63)
    const int ac = (t & 3) * 8;         // staging k-offset (bf16 elems)

    for (int k0 = 0; k0 < 1024; k0 += 32) {
        uint4 av  = *(const uint4*)(Ab + (long)(m0 + ar) * 1024 + k0 + ac);
        uint4 bv0 = *(const uint4*)(Bb + (long)(n0 + ar) * 1024 + k0 + ac);
        uint4 bv1 = *(const uint4*)(Bb + (long)(n0 + 64 + ar) * 1024 + k0 + ac);
        __syncthreads();                 // prior-iter LDS reads done
        *(uint4*)&As[t * 8]        = av;
        *(uint4*)&Bs[t * 8]        = bv0;
        *(uint4*)&Bs[2048 + t * 8] = bv1;
        __syncthreads();

        const int krow = (lane >> 4) * 8;
        bf16x8 af[2], bf[4];
#pragma unroll
        for (int fi = 0; fi < 2; ++fi)
            af[fi] = *(const bf16x8*)&As[(wm * 32 + fi * 16 + (lane & 15)) * 32 + krow];
#pragma unroll
        for (int fj = 0; fj < 4; ++fj)
            bf[fj] = *(const bf16x8*)&Bs[(wn * 64 + fj * 16 + (lane & 15)) * 32 + krow];
#pragma unroll
        for (int fi = 0; fi < 2; ++fi)
#pragma unroll
            for (int fj = 0; fj < 4; ++fj)
                acc[fi][fj] = __builtin_amdgcn_mfma_f32_16x16x32_bf16(
                    af[fi], bf[fj], acc[fi][fj], 0, 0, 0);
    }

    const int rbase = (lane >> 4) * 4;
    const int cn    = n0 + wn * 64 + (lane & 15);
#pragma unroll
    for (int fi = 0; fi < 2; ++fi) {
        const int mb = m0 + wm * 32 + fi * 16 + rbase;
#pragma unroll
        for (int r = 0; r < 4; ++r) {
            const int m = mb + r;
            if (m < M) {
#pragma unroll
                for (int fj = 0; fj < 4; ++fj)
                    Cb[(long)m * 1024 + cn + fj * 16] = acc[fi][fj][r];
            }
        }
    }
}

// ---------------- fused convert: v_bf[b][l][e] and v_bfT[b][e][l] from fp32
__global__ __launch_bounds__(256) void cvt_k(
    const float* __restrict__ vf, unsigned short* __restrict__ vbf,
    unsigned short* __restrict__ vbfT)
{
    const int b  = blockIdx.z;
    const int e0 = blockIdx.x * 64;
    const int l0 = blockIdx.y * 64;
    const float* src = vf + (long)b * 4194304;   // batch stride = T*L*D
    __shared__ unsigned short tile[64][72];
    const int t = threadIdx.x;
    const int r0 = t >> 4, c0 = (t & 15) * 4;
#pragma unroll
    for (int rr = 0; rr < 4; ++rr) {
        const int r = r0 + rr * 16;
        float4 v = *(const float4*)&src[(long)(l0 + r) * 1024 + e0 + c0];
        ushort4 o;
        o.x = f2bf(v.x); o.y = f2bf(v.y); o.z = f2bf(v.z); o.w = f2bf(v.w);
        tile[r][c0 + 0] = o.x; tile[r][c0 + 1] = o.y;
        tile[r][c0 + 2] = o.z; tile[r][c0 + 3] = o.w;
        *(ushort4*)&vbf[(long)b * 1048576 + (long)(l0 + r) * 1024 + e0 + c0] = o;
    }
    __syncthreads();
#pragma unroll
    for (int rr = 0; rr < 4; ++rr) {
        const int idx = rr * 256 + t;
        const int e   = idx >> 4;
        const int c4  = (idx & 15) * 4;
        ushort4 o;
        o.x = tile[c4 + 0][e]; o.y = tile[c4 + 1][e];
        o.z = tile[c4 + 2][e]; o.w = tile[c4 + 3][e];
        *(ushort4*)&vbfT[(long)b * 1048576 + (long)(e0 + e) * 1024 + l0 + c4] = o;
    }
}

// ---------------- query[b,n,d] = emb[max(node,0)][d] + bboxes . Wb[d,:] + bb[d]
__global__ __launch_bounds__(256) void build_query_k(
    const int* __restrict__ nodes, const float* __restrict__ bboxes,
    const float* __restrict__ emb, const float* __restrict__ Wb,
    const float* __restrict__ bb, float* __restrict__ query)
{
    const int blk = blockIdx.x;
    const int node = nodes[blk];
    const int idx = node < 0 ? 0 : node;
    const float4 bx = *(const float4*)&bboxes[blk * 4];
    const float* er = emb + (long)idx * 1024;
    for (int d = threadIdx.x; d < 1024; d += 256) {
        const float4 w = *(const float4*)&Wb[d * 4];
        query[(long)blk * 1024 + d] =
            er[d] + bb[d] + bx.x * w.x + bx.y * w.y + bx.z * w.z + bx.w * w.w;
    }
}

// ---------------- row softmax over 1024; fp32 in, bf16 out (padded 128 rows/b)
__global__ __launch_bounds__(256) void softmax_k(
    const float* __restrict__ sc, unsigned short* __restrict__ attn)
{
    __shared__ float red[4];
    const int blk = blockIdx.x;              // b*120 + r
    const int b = blk / 120, r = blk % 120;
    const float* p = sc + (long)blk * 1024;
    const int t = threadIdx.x;
    float4 v = *(const float4*)&p[t * 4];

    float m = fmaxf(fmaxf(v.x, v.y), fmaxf(v.z, v.w));
#pragma unroll
    for (int o = 32; o; o >>= 1) m = fmaxf(m, __shfl_xor(m, o));
    if ((t & 63) == 0) red[t >> 6] = m;
    __syncthreads();
    m = fmaxf(fmaxf(red[0], red[1]), fmaxf(red[2], red[3]));
    __syncthreads();

    v.x = __expf(v.x - m); v.y = __expf(v.y - m);
    v.z = __expf(v.z - m); v.w = __expf(v.w - m);
    float s = v.x + v.y + v.z + v.w;
#pragma unroll
    for (int o = 32; o; o >>= 1) s += __shfl_xor(s, o);
    if ((t & 63) == 0) red[t >> 6] = s;
    __syncthreads();
    s = red[0] + red[1] + red[2] + red[3];
    const float inv = 1.0f / s;
    ushort4 o;
    o.x = f2bf(v.x * inv); o.y = f2bf(v.y * inv);
    o.z = f2bf(v.z * inv); o.w = f2bf(v.w * inv);
    *(ushort4*)&attn[(long)(b * 128 + r) * 1024 + t * 4] = o;
}

// ---------------- edge head: one block per (b, i). thread = (j, c).
__global__ __launch_bounds__(320) void edge_k(
    const float* __restrict__ hi, const float* __restrict__ hj,
    const float* __restrict__ W2, const float* __restrict__ b2,
    float* __restrict__ out)
{
    const int b = blockIdx.x, i = blockIdx.y;
    const int t = threadIdx.x;
    __shared__ float hiS[256];
    __shared__ float hjS[15][257];
    __shared__ float w2S[18][257];
    const int j = t / 18, c = t % 18;
    float acc = 0.0f;

    for (int u0 = 0; u0 < 512; u0 += 256) {
        __syncthreads();
        if (t < 64) {
            float4 v = *(const float4*)&hi[(long)(b * 15 + i) * 512 + u0 + t * 4];
            hiS[t * 4 + 0] = v.x; hiS[t * 4 + 1] = v.y;
            hiS[t * 4 + 2] = v.z; hiS[t * 4 + 3] = v.w;
        }
        for (int x = t; x < 960; x += 320) {
            const int r = x >> 6, cc = (x & 63) * 4;
            float4 v = *(const float4*)&hj[(long)(b * 15 + r) * 512 + u0 + cc];
            hjS[r][cc + 0] = v.x; hjS[r][cc + 1] = v.y;
            hjS[r][cc + 2] = v.z; hjS[r][cc + 3] = v.w;
        }
        for (int x = t; x < 1152; x += 320) {
            const int r = x >> 6, cc = (x & 63) * 4;
            float4 v = *(const float4*)&W2[(long)r * 512 + u0 + cc];
            w2S[r][cc + 0] = v.x; w2S[r][cc + 1] = v.y;
            w2S[r][cc + 2] = v.z; w2S[r][cc + 3] = v.w;
        }
        __syncthreads();
        if (t < 270) {
            for (int u = 0; u < 256; ++u) {
                float p = hiS[u] + hjS[j][u];
                p = p > 0.0f ? p : 0.0f;
                acc += p * w2S[c][u];
            }
        }
    }
    if (t < 270)
        out[((long)(b * 15 + i) * 15 + j) * 18 + c] = acc + b2[c];
}

// ---------------- energy stage 1
__global__ __launch_bounds__(256) void energy1_k(
    const float* __restrict__ enr, const int* __restrict__ nodes,
    float* __restrict__ gfeat)
{
    const int b = blockIdx.y;
    const int e = blockIdx.x * 256 + threadIdx.x;
    int cnt = 0;
#pragma unroll
    for (int n = 0; n < 15; ++n) cnt += (nodes[b * 15 + n] != -1) ? 1 : 0;
    const float inv_valid = 1.0f / fmaxf((float)cnt, 1.0f);
    float s = 0.0f;
#pragma unroll
    for (int n = 0; n < 15; ++n) {
        const bool ok = nodes[b * 15 + n] != -1;
        s += ok ? enr[(long)(b * 15 + n) * 1024 + e] : 0.0f;
    }
    gfeat[b * 1024 + e] = s * inv_valid;
}

// ---------------- energy stage 2
__global__ __launch_bounds__(256) void energy2_k(
    const float* __restrict__ gfeat, const float* __restrict__ Wh1,
    const float* __restrict__ bh1, const float* __restrict__ Wh2,
    float* __restrict__ hidr)
{
    const int b  = blockIdx.y;
    const int u0 = blockIdx.x * 16;
    const int t = threadIdx.x;
    __shared__ float gf[1024];
    {
        float4 v = *(const float4*)&gfeat[b * 1024 + t * 4];
        gf[t * 4 + 0] = v.x; gf[t * 4 + 1] = v.y;
        gf[t * 4 + 2] = v.z; gf[t * 4 + 3] = v.w;
    }
    __syncthreads();
    const int wave = t >> 6, lane = t & 63;
#pragma unroll
    for (int r = 0; r < 4; ++r) {
        const int u = u0 + wave * 4 + r;
        float s = 0.0f;
#pragma unroll
        for (int e0 = 0; e0 < 1024; e0 += 64)
            s += gf[e0 + lane] * Wh1[(long)u * 1024 + e0 + lane];
#pragma unroll
        for (int o = 32; o; o >>= 1) s += __shfl_xor(s, o);
        if (lane == 0)
            hidr[b * 256 + u] = fmaxf(s + bh1[u], 0.0f) * Wh2[u];
    }
}

// ---------------- energy stage 3
__global__ __launch_bounds__(256) void energy3_k(
    const float* __restrict__ hidr, const float* __restrict__ bh2,
    float* __restrict__ out)
{
    const int b = blockIdx.x;
    const int t = threadIdx.x;
    __shared__ float red[4];
    float v = hidr[b * 256 + t];
#pragma unroll
    for (int o = 32; o; o >>= 1) v += __shfl_xor(v, o);
    if ((t & 63) == 0) red[t >> 6] = v;
    __syncthreads();
    if (t == 0) out[129600 + b] = red[0] + red[1] + red[2] + red[3] + bh2[0];
}

// ---------------------------------------------------------------------------
extern "C" void kernel_launch(void* const* d_in, const int* in_sizes, int n_in,
                              void* d_out, int out_size, void* d_ws, size_t ws_size,
                              hipStream_t stream)
{
    const float* visual = (const float*)d_in[0];
    const int*   nodes  = (const int*)  d_in[1];
    const float* bboxes = (const float*)d_in[2];
    const float* emb    = (const float*)d_in[3];
    const float* Wb     = (const float*)d_in[4];
    const float* bb     = (const float*)d_in[5];
    const float* Wq     = (const float*)d_in[6];
    const float* bq     = (const float*)d_in[7];
    const float* Wk     = (const float*)d_in[8];
    /* bk (d_in[9]) cancels in softmax */
    const float* Wv     = (const float*)d_in[10];
    const float* bv     = (const float*)d_in[11];
    const float* Wo     = (const float*)d_in[12];
    const float* bo     = (const float*)d_in[13];
    const float* W1     = (const float*)d_in[14];
    const float* b1     = (const float*)d_in[15];
    const float* W2     = (const float*)d_in[16];
    const float* b2     = (const float*)d_in[17];
    const float* Wh1    = (const float*)d_in[18];
    const float* bh1    = (const float*)d_in[19];
    const float* Wh2    = (const float*)d_in[20];
    const float* bh2    = (const float*)d_in[21];

    float* out = (float*)d_out;
    float* ws  = (float*)d_ws;

    // workspace layout (fp32 units)
    float* query  = ws;                       // 480*1024
    float* q      = ws + 491520;              // 480*1024
    float* scores = ws + 983040;              // 32*120*1024 fp32
    float* ctxf   = ws + 4915200;             // 32*120*1024 fp32
    float* ctx    = ws + 8847360;             // 480*1024
    float* enr    = ws + 9338880;             // 480*1024
    float* hi     = ws + 9830400;             // 480*512
    float* hj     = ws + 10076160;            // 480*512
    unsigned short* qW_bf   = (unsigned short*)(ws + 10321920); // 32*128*1024 bf16
    unsigned short* attn_bf = (unsigned short*)(ws + 12419072); // 32*128*1024 bf16
    unsigned short* v_bf    = (unsigned short*)(ws + 14516224); // 32*1024*1024 bf16
    unsigned short* v_bfT   = (unsigned short*)(ws + 31293440); // 32*1024*1024 bf16
    float* gfeat  = query;                    // alias (query dead after q GEMM)
    float* hidr   = query + 32768;            // alias

    const float inv_sqrt_hd = 0.08838834764831845f;  // 1/sqrt(128)
    const float* v_f = visual + 3 * 1048576;         // frame T-1; batch stride 4*1048576

    // 1) query build + v_f bf16 conversion (row + transposed)
    build_query_k<<<480, 256, 0, stream>>>(nodes, bboxes, emb, Wb, bb, query);
    cvt_k<<<dim3(16, 16, 32), 256, 0, stream>>>(v_f, v_bf, v_bfT);

    // 2) q = query @ Wq^T + bq            (480 x 1024, K=1024, fp32)
    gemm_k<64, 64, 16, 4, 4, true><<<dim3(16, 8, 1), 256, 0, stream>>>(
        query, Wq, bq, q, 480, 1024, 1024, 1024, 1024, 1024,
        0, 0, 0, 0, 1, 0, 0, 0, 0, 1.0f);

    // 3) qW_bf[b][(n,h)][e] = (q[b,n,h-slice] @ Wk[h-slice,:]) * inv_sqrt_hd
    gemm_k<16, 64, 32, 1, 4, false, true><<<dim3(16, 1, 256), 256, 0, stream>>>(
        q, Wk, nullptr, qW_bf, 15, 1024, 128, 1024, 1024, 8192,
        15360, 0, 131072, 0, 8, 128, 131072, 1024, 0, inv_sqrt_hd);

    // 4) scores[b] = qW_bf[b] @ v_bf[b]^T   (MFMA) + 3 replica launches
    //    [INSTRUMENTATION: replicas are idempotent rewrites of `scores`]
    for (int rep = 0; rep < 4; ++rep)
        bfgemm_k<<<dim3(8, 2, 32), 256, 0, stream>>>(
            qW_bf, v_bf, scores, 120, 131072, 1048576, 122880);

    // 5) softmax over l -> bf16 attn (padded 128 rows/b)
    softmax_k<<<3840, 256, 0, stream>>>(scores, attn_bf);

    // 6) ctxf[b] = attn[b] @ v_bfT[b]^T     (MFMA) + 3 replica launches
    for (int rep = 0; rep < 4; ++rep)
        bfgemm_k<<<dim3(8, 2, 32), 256, 0, stream>>>(
            attn_bf, v_bfT, ctxf, 120, 131072, 1048576, 122880);

    // 7) ctx[b,:,h] = ctxf[b,(:,h),:] @ Wv_h^T + bv_h   (fp32)
    gemm_k<16, 64, 32, 1, 4, true><<<dim3(2, 1, 256), 256, 0, stream>>>(
        ctxf, Wv, bv, ctx, 15, 128, 1024, 8192, 1024, 1024,
        122880, 0, 15360, 0, 8, 1024, 131072, 128, 128, 1.0f);

    // 8) enriched = ctx @ Wo^T + bo        (480 x 1024, K=1024, fp32)
    gemm_k<64, 64, 16, 4, 4, true><<<dim3(16, 8, 1), 256, 0, stream>>>(
        ctx, Wo, bo, enr, 480, 1024, 1024, 1024, 1024, 1024,
        0, 0, 0, 0, 1, 0, 0, 0, 0, 1.0f);

    // 9) hi = enr @ W1[:, :1024]^T + b1 ;  hj = enr @ W1[:, 1024:]^T  (fp32)
    gemm_k<64, 64, 16, 4, 4, true><<<dim3(8, 8, 1), 256, 0, stream>>>(
        enr, W1, b1, hi, 480, 512, 1024, 1024, 2048, 512,
        0, 0, 0, 0, 1, 0, 0, 0, 0, 1.0f);
    gemm_k<64, 64, 16, 4, 4, true><<<dim3(8, 8, 1), 256, 0, stream>>>(
        enr, W1 + 1024, nullptr, hj, 480, 512, 1024, 1024, 2048, 512,
        0, 0, 0, 0, 1, 0, 0, 0, 0, 1.0f);

    // 10) edge logits -> out[0 .. 129600)
    edge_k<<<dim3(32, 15, 1), 320, 0, stream>>>(hi, hj, W2, b2, out);

    // 11) energy -> out[129600 .. 129632)
    energy1_k<<<dim3(4, 32, 1), 256, 0, stream>>>(enr, nodes, gfeat);
    energy2_k<<<dim3(16, 32, 1), 256, 0, stream>>>(gfeat, Wh1, bh1, Wh2, hidr);
    energy3_k<<<32, 256, 0, stream>>>(hidr, bh2, out);
}

// Round 10
// 329.538 us; speedup vs baseline: 1.9990x; 1.9990x over previous
//
#include <hip/hip_runtime.h>
#include <type_traits>

// ---------------------------------------------------------------------------
// RelationalTransformer: B=32 T=4 L=1024 D=1024 H=8 Hd=128 N=15
// out = edge_logits (32*15*15*18 = 129600) ++ energy (32)   [fp32]
//
// R10: bfgemm pair measured at 49us (R9 replica instrumentation) -> the fp32
// projection GEMMs (~190us) are the real hog. Convert q/Wo/hi/hj to bf16
// MFMA (pgemm_k, 64x64 tile, v1-staging structure). Weights pre-converted.
// ---------------------------------------------------------------------------

typedef __attribute__((ext_vector_type(8))) short bf16x8;   // 8 bf16 in 4 VGPRs
typedef __attribute__((ext_vector_type(4))) float f32x4;

__device__ __forceinline__ unsigned short f2bf(float f) {   // RNE float->bf16
    unsigned int u = __float_as_uint(f);
    u = u + 0x7FFFu + ((u >> 16) & 1u);
    return (unsigned short)(u >> 16);
}

// ---------------- generic strided-batched fp32 GEMM (qW / Wv only now)
template <int BM, int BN, int BK, int TM, int TN, bool BT, bool OUTBF = false>
__global__ __launch_bounds__(256) void gemm_k(
    const float* __restrict__ A, const float* __restrict__ B,
    const float* __restrict__ bias, void* __restrict__ Cv,
    int M, int N, int K, int lda, int ldb, int ldc,
    long sA1, long sB1, long sC1, long sb1,
    int batch2, long sA2, long sB2, long sC2, long sb2,
    float alpha)
{
    using OutT = typename std::conditional<OUTBF, unsigned short, float>::type;
    const int z  = blockIdx.z;
    const int z1 = z / batch2, z2 = z % batch2;
    A += z1 * sA1 + z2 * sA2;
    B += z1 * sB1 + z2 * sB2;
    OutT* C = ((OutT*)Cv) + z1 * sC1 + z2 * sC2;
    const float* bp = bias ? (bias + z1 * sb1 + z2 * sb2) : nullptr;

    const int m0 = blockIdx.y * BM;
    const int n0 = blockIdx.x * BN;

    __shared__ float As[BK * BM];
    __shared__ float Bs[BK * BN];

    const int t   = threadIdx.x;
    const int TNW = BN / TN;
    const int tn  = t % TNW;
    const int tm  = t / TNW;

    float acc[TM][TN];
#pragma unroll
    for (int i = 0; i < TM; ++i)
#pragma unroll
        for (int j = 0; j < TN; ++j) acc[i][j] = 0.0f;

    for (int k0 = 0; k0 < K; k0 += BK) {
        constexpr int ACH = BM * BK / 4;
        for (int c = t; c < ACH; c += 256) {
            const int flat = c * 4;
            const int kq = flat % BK, m = flat / BK;
            float4 v = make_float4(0.f, 0.f, 0.f, 0.f);
            if (m0 + m < M)
                v = *(const float4*)&A[(long)(m0 + m) * lda + k0 + kq];
            As[(kq + 0) * BM + m] = v.x;
            As[(kq + 1) * BM + m] = v.y;
            As[(kq + 2) * BM + m] = v.z;
            As[(kq + 3) * BM + m] = v.w;
        }
        constexpr int BCH = BN * BK / 4;
        if constexpr (BT) {
            for (int c = t; c < BCH; c += 256) {
                const int flat = c * 4;
                const int kq = flat % BK, n = flat / BK;
                float4 v = *(const float4*)&B[(long)(n0 + n) * ldb + k0 + kq];
                Bs[(kq + 0) * BN + n] = v.x;
                Bs[(kq + 1) * BN + n] = v.y;
                Bs[(kq + 2) * BN + n] = v.z;
                Bs[(kq + 3) * BN + n] = v.w;
            }
        } else {
            for (int c = t; c < BCH; c += 256) {
                const int flat = c * 4;
                const int n = flat % BN, kq = flat / BN;
                float4 v = *(const float4*)&B[(long)(k0 + kq) * ldb + n0 + n];
                *(float4*)&Bs[kq * BN + n] = v;
            }
        }
        __syncthreads();

#pragma unroll
        for (int kk = 0; kk < BK; ++kk) {
            float a[TM], bvv[TN];
            if constexpr (TM == 4) {
                float4 v = *(const float4*)&As[kk * BM + tm * 4];
                a[0] = v.x; a[1] = v.y; a[2] = v.z; a[3] = v.w;
            } else {
#pragma unroll
                for (int i = 0; i < TM; ++i) a[i] = As[kk * BM + tm * TM + i];
            }
            if constexpr (TN == 4) {
                float4 v = *(const float4*)&Bs[kk * BN + tn * 4];
                bvv[0] = v.x; bvv[1] = v.y; bvv[2] = v.z; bvv[3] = v.w;
            } else {
#pragma unroll
                for (int j = 0; j < TN; ++j) bvv[j] = Bs[kk * BN + tn * TN + j];
            }
#pragma unroll
            for (int i = 0; i < TM; ++i)
#pragma unroll
                for (int j = 0; j < TN; ++j) acc[i][j] += a[i] * bvv[j];
        }
        __syncthreads();
    }

#pragma unroll
    for (int i = 0; i < TM; ++i) {
        const int m = m0 + tm * TM + i;
        if (m >= M) continue;
#pragma unroll
        for (int j = 0; j < TN; ++j) {
            const int n = n0 + tn * TN + j;
            float v = acc[i][j] * alpha;
            if (bp) v += bp[n];
            if constexpr (OUTBF)
                C[(long)m * ldc + n] = f2bf(v);
            else
                C[(long)m * ldc + n] = v;
        }
    }
}

// ---------------- bf16 MFMA GEMM v1 (measured 24.5us/call): 64x128 tile
__global__ __launch_bounds__(256) void bfgemm_k(
    const unsigned short* __restrict__ A, const unsigned short* __restrict__ B,
    float* __restrict__ C, int M, long sA, long sB, long sC)
{
    const int b  = blockIdx.z;
    const int m0 = blockIdx.y * 64;
    const int n0 = blockIdx.x * 128;
    const unsigned short* Ab = A + b * sA;
    const unsigned short* Bb = B + b * sB;
    float* Cb = C + b * sC;

    __shared__ __align__(16) unsigned short As[64 * 32];   // [m][k]
    __shared__ __align__(16) unsigned short Bs[128 * 32];  // [n][k]

    const int t    = threadIdx.x;
    const int lane = t & 63;
    const int w    = t >> 6;
    const int wm   = w >> 1, wn = w & 1;       // wave tile: 32 x 64

    f32x4 acc[2][4] = {};

    const int ar = t >> 2;              // staging row (0..63)
    const int ac = (t & 3) * 8;         // staging k-offset (bf16 elems)

    for (int k0 = 0; k0 < 1024; k0 += 32) {
        uint4 av  = *(const uint4*)(Ab + (long)(m0 + ar) * 1024 + k0 + ac);
        uint4 bv0 = *(const uint4*)(Bb + (long)(n0 + ar) * 1024 + k0 + ac);
        uint4 bv1 = *(const uint4*)(Bb + (long)(n0 + 64 + ar) * 1024 + k0 + ac);
        __syncthreads();                 // prior-iter LDS reads done
        *(uint4*)&As[t * 8]        = av;
        *(uint4*)&Bs[t * 8]        = bv0;
        *(uint4*)&Bs[2048 + t * 8] = bv1;
        __syncthreads();

        const int krow = (lane >> 4) * 8;
        bf16x8 af[2], bf[4];
#pragma unroll
        for (int fi = 0; fi < 2; ++fi)
            af[fi] = *(const bf16x8*)&As[(wm * 32 + fi * 16 + (lane & 15)) * 32 + krow];
#pragma unroll
        for (int fj = 0; fj < 4; ++fj)
            bf[fj] = *(const bf16x8*)&Bs[(wn * 64 + fj * 16 + (lane & 15)) * 32 + krow];
#pragma unroll
        for (int fi = 0; fi < 2; ++fi)
#pragma unroll
            for (int fj = 0; fj < 4; ++fj)
                acc[fi][fj] = __builtin_amdgcn_mfma_f32_16x16x32_bf16(
                    af[fi], bf[fj], acc[fi][fj], 0, 0, 0);
    }

    const int rbase = (lane >> 4) * 4;
    const int cn    = n0 + wn * 64 + (lane & 15);
#pragma unroll
    for (int fi = 0; fi < 2; ++fi) {
        const int mb = m0 + wm * 32 + fi * 16 + rbase;
#pragma unroll
        for (int r = 0; r < 4; ++r) {
            const int m = mb + r;
            if (m < M) {
#pragma unroll
                for (int fj = 0; fj < 4; ++fj)
                    Cb[(long)m * 1024 + cn + fj * 16] = acc[fi][fj][r];
            }
        }
    }
}

// ---------------- projection bf16 MFMA GEMM: C[m][n] = sum_k A[m][k]*B[n][k]
// Tile 64x64, 4 waves (2x2), wave tile 32x32. Same staging structure as
// bfgemm v1. A: Mpad x lda bf16 (pad rows garbage, stores guarded);
// B: N x ldb bf16 (weights). C fp32 + optional bf16 mirror + bias.
template <bool DUAL>
__global__ __launch_bounds__(256) void pgemm_k(
    const unsigned short* __restrict__ A, const unsigned short* __restrict__ B,
    const float* __restrict__ bias, float* __restrict__ C,
    unsigned short* __restrict__ Cbf,
    int M, int K, int lda, int ldb, int ldc)
{
    const int m0 = blockIdx.y * 64;
    const int n0 = blockIdx.x * 64;

    __shared__ __align__(16) unsigned short As[64 * 32];
    __shared__ __align__(16) unsigned short Bs[64 * 32];

    const int t    = threadIdx.x;
    const int lane = t & 63;
    const int w    = t >> 6;
    const int wm   = w >> 1, wn = w & 1;   // wave tile: 32 x 32
    const int lm   = lane & 15, lg = lane >> 4;

    const int ar = t >> 2;
    const int ac = (t & 3) * 8;

    f32x4 acc[2][2] = {};

    for (int k0 = 0; k0 < K; k0 += 32) {
        uint4 av = *(const uint4*)(A + (long)(m0 + ar) * lda + k0 + ac);
        uint4 bv = *(const uint4*)(B + (long)(n0 + ar) * ldb + k0 + ac);
        __syncthreads();
        *(uint4*)&As[t * 8] = av;
        *(uint4*)&Bs[t * 8] = bv;
        __syncthreads();

        const int krow = lg * 8 & 24;   // (lane>>4)*8, 0..24
        bf16x8 af[2], bf[2];
#pragma unroll
        for (int fi = 0; fi < 2; ++fi)
            af[fi] = *(const bf16x8*)&As[(wm * 32 + fi * 16 + lm) * 32 + krow];
#pragma unroll
        for (int fj = 0; fj < 2; ++fj)
            bf[fj] = *(const bf16x8*)&Bs[(wn * 32 + fj * 16 + lm) * 32 + krow];
#pragma unroll
        for (int fi = 0; fi < 2; ++fi)
#pragma unroll
            for (int fj = 0; fj < 2; ++fj)
                acc[fi][fj] = __builtin_amdgcn_mfma_f32_16x16x32_bf16(
                    af[fi], bf[fj], acc[fi][fj], 0, 0, 0);
    }

    const int rbase = lg * 4;
#pragma unroll
    for (int fi = 0; fi < 2; ++fi) {
        const int mb = m0 + wm * 32 + fi * 16 + rbase;
#pragma unroll
        for (int r = 0; r < 4; ++r) {
            const int m = mb + r;
            if (m < M) {
#pragma unroll
                for (int fj = 0; fj < 2; ++fj) {
                    const int n = n0 + wn * 32 + fj * 16 + lm;
                    float v = acc[fi][fj][r];
                    if (bias) v += bias[n];
                    C[(long)m * ldc + n] = v;
                    if constexpr (DUAL) Cbf[(long)m * ldc + n] = f2bf(v);
                }
            }
        }
    }
}

// ---------------- fp32 -> bf16 elementwise (weight conversion)
__global__ __launch_bounds__(256) void cvt1_k(
    const float* __restrict__ src, unsigned short* __restrict__ dst, int n4)
{
    const int i = blockIdx.x * 256 + threadIdx.x;
    if (i < n4) {
        float4 v = *(const float4*)&src[i * 4];
        ushort4 o;
        o.x = f2bf(v.x); o.y = f2bf(v.y); o.z = f2bf(v.z); o.w = f2bf(v.w);
        *(ushort4*)&dst[i * 4] = o;
    }
}

// ---------------- fused convert: v_bf[b][l][e] and v_bfT[b][e][l] from fp32
__global__ __launch_bounds__(256) void cvt_k(
    const float* __restrict__ vf, unsigned short* __restrict__ vbf,
    unsigned short* __restrict__ vbfT)
{
    const int b  = blockIdx.z;
    const int e0 = blockIdx.x * 64;
    const int l0 = blockIdx.y * 64;
    const float* src = vf + (long)b * 4194304;   // batch stride = T*L*D
    __shared__ unsigned short tile[64][72];
    const int t = threadIdx.x;
    const int r0 = t >> 4, c0 = (t & 15) * 4;
#pragma unroll
    for (int rr = 0; rr < 4; ++rr) {
        const int r = r0 + rr * 16;
        float4 v = *(const float4*)&src[(long)(l0 + r) * 1024 + e0 + c0];
        ushort4 o;
        o.x = f2bf(v.x); o.y = f2bf(v.y); o.z = f2bf(v.z); o.w = f2bf(v.w);
        tile[r][c0 + 0] = o.x; tile[r][c0 + 1] = o.y;
        tile[r][c0 + 2] = o.z; tile[r][c0 + 3] = o.w;
        *(ushort4*)&vbf[(long)b * 1048576 + (long)(l0 + r) * 1024 + e0 + c0] = o;
    }
    __syncthreads();
#pragma unroll
    for (int rr = 0; rr < 4; ++rr) {
        const int idx = rr * 256 + t;
        const int e   = idx >> 4;
        const int c4  = (idx & 15) * 4;
        ushort4 o;
        o.x = tile[c4 + 0][e]; o.y = tile[c4 + 1][e];
        o.z = tile[c4 + 2][e]; o.w = tile[c4 + 3][e];
        *(ushort4*)&vbfT[(long)b * 1048576 + (long)(e0 + e) * 1024 + l0 + c4] = o;
    }
}

// ---------------- query_bf[b,n,d] = bf16(emb[..] + bboxes.Wb[d,:] + bb[d])
__global__ __launch_bounds__(256) void build_query_k(
    const int* __restrict__ nodes, const float* __restrict__ bboxes,
    const float* __restrict__ emb, const float* __restrict__ Wb,
    const float* __restrict__ bb, unsigned short* __restrict__ qbf)
{
    const int blk = blockIdx.x;
    const int node = nodes[blk];
    const int idx = node < 0 ? 0 : node;
    const float4 bx = *(const float4*)&bboxes[blk * 4];
    const float* er = emb + (long)idx * 1024;
    for (int d = threadIdx.x; d < 1024; d += 256) {
        const float4 w = *(const float4*)&Wb[d * 4];
        qbf[(long)blk * 1024 + d] = f2bf(
            er[d] + bb[d] + bx.x * w.x + bx.y * w.y + bx.z * w.z + bx.w * w.w);
    }
}

// ---------------- row softmax over 1024; fp32 in, bf16 out (padded 128 rows/b)
__global__ __launch_bounds__(256) void softmax_k(
    const float* __restrict__ sc, unsigned short* __restrict__ attn)
{
    __shared__ float red[4];
    const int blk = blockIdx.x;              // b*120 + r
    const int b = blk / 120, r = blk % 120;
    const float* p = sc + (long)blk * 1024;
    const int t = threadIdx.x;
    float4 v = *(const float4*)&p[t * 4];

    float m = fmaxf(fmaxf(v.x, v.y), fmaxf(v.z, v.w));
#pragma unroll
    for (int o = 32; o; o >>= 1) m = fmaxf(m, __shfl_xor(m, o));
    if ((t & 63) == 0) red[t >> 6] = m;
    __syncthreads();
    m = fmaxf(fmaxf(red[0], red[1]), fmaxf(red[2], red[3]));
    __syncthreads();

    v.x = __expf(v.x - m); v.y = __expf(v.y - m);
    v.z = __expf(v.z - m); v.w = __expf(v.w - m);
    float s = v.x + v.y + v.z + v.w;
#pragma unroll
    for (int o = 32; o; o >>= 1) s += __shfl_xor(s, o);
    if ((t & 63) == 0) red[t >> 6] = s;
    __syncthreads();
    s = red[0] + red[1] + red[2] + red[3];
    const float inv = 1.0f / s;
    ushort4 o;
    o.x = f2bf(v.x * inv); o.y = f2bf(v.y * inv);
    o.z = f2bf(v.z * inv); o.w = f2bf(v.w * inv);
    *(ushort4*)&attn[(long)(b * 128 + r) * 1024 + t * 4] = o;
}

// ---------------- edge head: one block per (b, i). thread = (j, c).
__global__ __launch_bounds__(320) void edge_k(
    const float* __restrict__ hi, const float* __restrict__ hj,
    const float* __restrict__ W2, const float* __restrict__ b2,
    float* __restrict__ out)
{
    const int b = blockIdx.x, i = blockIdx.y;
    const int t = threadIdx.x;
    __shared__ float hiS[256];
    __shared__ float hjS[15][257];
    __shared__ float w2S[18][257];
    const int j = t / 18, c = t % 18;
    float acc = 0.0f;

    for (int u0 = 0; u0 < 512; u0 += 256) {
        __syncthreads();
        if (t < 64) {
            float4 v = *(const float4*)&hi[(long)(b * 15 + i) * 512 + u0 + t * 4];
            hiS[t * 4 + 0] = v.x; hiS[t * 4 + 1] = v.y;
            hiS[t * 4 + 2] = v.z; hiS[t * 4 + 3] = v.w;
        }
        for (int x = t; x < 960; x += 320) {
            const int r = x >> 6, cc = (x & 63) * 4;
            float4 v = *(const float4*)&hj[(long)(b * 15 + r) * 512 + u0 + cc];
            hjS[r][cc + 0] = v.x; hjS[r][cc + 1] = v.y;
            hjS[r][cc + 2] = v.z; hjS[r][cc + 3] = v.w;
        }
        for (int x = t; x < 1152; x += 320) {
            const int r = x >> 6, cc = (x & 63) * 4;
            float4 v = *(const float4*)&W2[(long)r * 512 + u0 + cc];
            w2S[r][cc + 0] = v.x; w2S[r][cc + 1] = v.y;
            w2S[r][cc + 2] = v.z; w2S[r][cc + 3] = v.w;
        }
        __syncthreads();
        if (t < 270) {
            for (int u = 0; u < 256; ++u) {
                float p = hiS[u] + hjS[j][u];
                p = p > 0.0f ? p : 0.0f;
                acc += p * w2S[c][u];
            }
        }
    }
    if (t < 270)
        out[((long)(b * 15 + i) * 15 + j) * 18 + c] = acc + b2[c];
}

// ---------------- energy stage 1
__global__ __launch_bounds__(256) void energy1_k(
    const float* __restrict__ enr, const int* __restrict__ nodes,
    float* __restrict__ gfeat)
{
    const int b = blockIdx.y;
    const int e = blockIdx.x * 256 + threadIdx.x;
    int cnt = 0;
#pragma unroll
    for (int n = 0; n < 15; ++n) cnt += (nodes[b * 15 + n] != -1) ? 1 : 0;
    const float inv_valid = 1.0f / fmaxf((float)cnt, 1.0f);
    float s = 0.0f;
#pragma unroll
    for (int n = 0; n < 15; ++n) {
        const bool ok = nodes[b * 15 + n] != -1;
        s += ok ? enr[(long)(b * 15 + n) * 1024 + e] : 0.0f;
    }
    gfeat[b * 1024 + e] = s * inv_valid;
}

// ---------------- energy stage 2
__global__ __launch_bounds__(256) void energy2_k(
    const float* __restrict__ gfeat, const float* __restrict__ Wh1,
    const float* __restrict__ bh1, const float* __restrict__ Wh2,
    float* __restrict__ hidr)
{
    const int b  = blockIdx.y;
    const int u0 = blockIdx.x * 16;
    const int t = threadIdx.x;
    __shared__ float gf[1024];
    {
        float4 v = *(const float4*)&gfeat[b * 1024 + t * 4];
        gf[t * 4 + 0] = v.x; gf[t * 4 + 1] = v.y;
        gf[t * 4 + 2] = v.z; gf[t * 4 + 3] = v.w;
    }
    __syncthreads();
    const int wave = t >> 6, lane = t & 63;
#pragma unroll
    for (int r = 0; r < 4; ++r) {
        const int u = u0 + wave * 4 + r;
        float s = 0.0f;
#pragma unroll
        for (int e0 = 0; e0 < 1024; e0 += 64)
            s += gf[e0 + lane] * Wh1[(long)u * 1024 + e0 + lane];
#pragma unroll
        for (int o = 32; o; o >>= 1) s += __shfl_xor(s, o);
        if (lane == 0)
            hidr[b * 256 + u] = fmaxf(s + bh1[u], 0.0f) * Wh2[u];
    }
}

// ---------------- energy stage 3
__global__ __launch_bounds__(256) void energy3_k(
    const float* __restrict__ hidr, const float* __restrict__ bh2,
    float* __restrict__ out)
{
    const int b = blockIdx.x;
    const int t = threadIdx.x;
    __shared__ float red[4];
    float v = hidr[b * 256 + t];
#pragma unroll
    for (int o = 32; o; o >>= 1) v += __shfl_xor(v, o);
    if ((t & 63) == 0) red[t >> 6] = v;
    __syncthreads();
    if (t == 0) out[129600 + b] = red[0] + red[1] + red[2] + red[3] + bh2[0];
}

// ---------------------------------------------------------------------------
extern "C" void kernel_launch(void* const* d_in, const int* in_sizes, int n_in,
                              void* d_out, int out_size, void* d_ws, size_t ws_size,
                              hipStream_t stream)
{
    const float* visual = (const float*)d_in[0];
    const int*   nodes  = (const int*)  d_in[1];
    const float* bboxes = (const float*)d_in[2];
    const float* emb    = (const float*)d_in[3];
    const float* Wb     = (const float*)d_in[4];
    const float* bb     = (const float*)d_in[5];
    const float* Wq     = (const float*)d_in[6];
    const float* bq     = (const float*)d_in[7];
    const float* Wk     = (const float*)d_in[8];
    /* bk (d_in[9]) cancels in softmax */
    const float* Wv     = (const float*)d_in[10];
    const float* bv     = (const float*)d_in[11];
    const float* Wo     = (const float*)d_in[12];
    const float* bo     = (const float*)d_in[13];
    const float* W1     = (const float*)d_in[14];
    const float* b1     = (const float*)d_in[15];
    const float* W2     = (const float*)d_in[16];
    const float* b2     = (const float*)d_in[17];
    const float* Wh1    = (const float*)d_in[18];
    const float* bh1    = (const float*)d_in[19];
    const float* Wh2    = (const float*)d_in[20];
    const float* bh2    = (const float*)d_in[21];

    float* out = (float*)d_out;
    float* ws  = (float*)d_ws;

    // workspace layout (offsets in fp32 units; bf16 buffers cast to ushort)
    unsigned short* query_bf = (unsigned short*)(ws);            // 512x1024 bf16
    float* q      = ws + 262144;              // 480*1024 f32
    float* scores = ws + 753664;              // 32*120*1024 f32
    float* ctxf   = ws + 4685824;             // 32*120*1024 f32
    unsigned short* ctx_bf = (unsigned short*)(ws + 8617984);    // 512x1024 bf16
    float* enr    = ws + 8880128;             // 480*1024 f32
    unsigned short* enr_bf = (unsigned short*)(ws + 9371648);    // 512x1024 bf16
    float* hi     = ws + 9633792;             // 480*512 f32
    float* hj     = ws + 9879552;             // 480*512 f32
    unsigned short* Wq_bf  = (unsigned short*)(ws + 10125312);   // 1024x1024 bf16
    unsigned short* Wo_bf  = (unsigned short*)(ws + 10649600);   // 1024x1024 bf16
    unsigned short* W1_bf  = (unsigned short*)(ws + 11173888);   // 512x2048 bf16
    unsigned short* qW_bf   = (unsigned short*)(ws + 11698176);  // 32*128*1024 bf16
    unsigned short* attn_bf = (unsigned short*)(ws + 13795328);  // 32*128*1024 bf16
    unsigned short* v_bf    = (unsigned short*)(ws + 15892480);  // 32*1024*1024 bf16
    unsigned short* v_bfT   = (unsigned short*)(ws + 32669696);  // 32*1024*1024 bf16
    float* gfeat  = ws + 49446912;            // 32*1024
    float* hidr   = ws + 49479680;            // 32*256

    const float inv_sqrt_hd = 0.08838834764831845f;  // 1/sqrt(128)
    const float* v_f = visual + 3 * 1048576;         // frame T-1; batch stride 4*1048576

    // 1) query build (bf16) + v_f bf16 conversion + weight conversions
    build_query_k<<<480, 256, 0, stream>>>(nodes, bboxes, emb, Wb, bb, query_bf);
    cvt_k<<<dim3(16, 16, 32), 256, 0, stream>>>(v_f, v_bf, v_bfT);
    cvt1_k<<<1024, 256, 0, stream>>>(Wq, Wq_bf, 262144);
    cvt1_k<<<1024, 256, 0, stream>>>(Wo, Wo_bf, 262144);
    cvt1_k<<<1024, 256, 0, stream>>>(W1, W1_bf, 262144);

    // 2) q = query_bf @ Wq_bf^T + bq      (MFMA, M=480 pad 512, N=1024)
    pgemm_k<false><<<dim3(16, 8, 1), 256, 0, stream>>>(
        query_bf, Wq_bf, bq, q, nullptr, 480, 1024, 1024, 1024, 1024);

    // 3) qW_bf[b][(n,h)][e] = (q[b,n,h-slice] @ Wk[h-slice,:]) * inv_sqrt_hd
    gemm_k<16, 64, 32, 1, 4, false, true><<<dim3(16, 1, 256), 256, 0, stream>>>(
        q, Wk, nullptr, qW_bf, 15, 1024, 128, 1024, 1024, 8192,
        15360, 0, 131072, 0, 8, 128, 131072, 1024, 0, inv_sqrt_hd);

    // 4) scores[b] = qW_bf[b] @ v_bf[b]^T   (MFMA, M=120 pad 128, N=1024)
    bfgemm_k<<<dim3(8, 2, 32), 256, 0, stream>>>(
        qW_bf, v_bf, scores, 120, 131072, 1048576, 122880);

    // 5) softmax over l -> bf16 attn (padded 128 rows/b)
    softmax_k<<<3840, 256, 0, stream>>>(scores, attn_bf);

    // 6) ctxf[b] = attn[b] @ v_bfT[b]^T     (MFMA, K=1024 over tokens)
    bfgemm_k<<<dim3(8, 2, 32), 256, 0, stream>>>(
        attn_bf, v_bfT, ctxf, 120, 131072, 1048576, 122880);

    // 7) ctx_bf[b,:,h] = bf16(ctxf[b,(:,h),:] @ Wv_h^T + bv_h)   (fp32 gemm)
    gemm_k<16, 64, 32, 1, 4, true, true><<<dim3(2, 1, 256), 256, 0, stream>>>(
        ctxf, Wv, bv, ctx_bf, 15, 128, 1024, 8192, 1024, 1024,
        122880, 0, 15360, 0, 8, 1024, 131072, 128, 128, 1.0f);

    // 8) enr = ctx_bf @ Wo_bf^T + bo  (MFMA, dual fp32+bf16 output)
    pgemm_k<true><<<dim3(16, 8, 1), 256, 0, stream>>>(
        ctx_bf, Wo_bf, bo, enr, enr_bf, 480, 1024, 1024, 1024, 1024);

    // 9) hi = enr_bf @ W1_bf[:, :1024]^T + b1 ; hj = enr_bf @ W1_bf[:,1024:]^T
    pgemm_k<false><<<dim3(8, 8, 1), 256, 0, stream>>>(
        enr_bf, W1_bf, b1, hi, nullptr, 480, 1024, 1024, 2048, 512);
    pgemm_k<false><<<dim3(8, 8, 1), 256, 0, stream>>>(
        enr_bf, W1_bf + 1024, nullptr, hj, nullptr, 480, 1024, 1024, 2048, 512);

    // 10) edge logits -> out[0 .. 129600)
    edge_k<<<dim3(32, 15, 1), 320, 0, stream>>>(hi, hj, W2, b2, out);

    // 11) energy -> out[129600 .. 129632)
    energy1_k<<<dim3(4, 32, 1), 256, 0, stream>>>(enr, nodes, gfeat);
    energy2_k<<<dim3(16, 32, 1), 256, 0, stream>>>(gfeat, Wh1, bh1, Wh2, hidr);
    energy3_k<<<32, 256, 0, stream>>>(hidr, bh2, out);
}

// Round 11
// 245.524 us; speedup vs baseline: 2.6830x; 1.3422x over previous
//
#include <hip/hip_runtime.h>

// ---------------------------------------------------------------------------
// RelationalTransformer: B=32 T=4 L=1024 D=1024 H=8 Hd=128 N=15
// out = edge_logits (32*15*15*18 = 129600) ++ energy (32)   [fp32]
//
// R11: all GEMMs now bf16 MFMA. New qw_k / ctx_k replace the last two fp32
// GEMMs (measured-estimated 60-100us). hi+hj fused into one pgemm via W1
// reshape; b1 applied in edge_k.
// ---------------------------------------------------------------------------

typedef __attribute__((ext_vector_type(8))) short bf16x8;   // 8 bf16 in 4 VGPRs
typedef __attribute__((ext_vector_type(4))) float f32x4;

__device__ __forceinline__ unsigned short f2bf(float f) {   // RNE float->bf16
    unsigned int u = __float_as_uint(f);
    u = u + 0x7FFFu + ((u >> 16) & 1u);
    return (unsigned short)(u >> 16);
}

// ---------------- bf16 MFMA GEMM (64x128 tile, 4 waves): C = A @ B^T
// OUTBF: write bf16 C (sC/ldc then in ushort units).
template <bool OUTBF>
__global__ __launch_bounds__(256) void bfgemm_k(
    const unsigned short* __restrict__ A, const unsigned short* __restrict__ B,
    void* __restrict__ Cv, int M, long sA, long sB, long sC)
{
    const int b  = blockIdx.z;
    const int m0 = blockIdx.y * 64;
    const int n0 = blockIdx.x * 128;
    const unsigned short* Ab = A + b * sA;
    const unsigned short* Bb = B + b * sB;

    __shared__ __align__(16) unsigned short As[64 * 32];   // [m][k]
    __shared__ __align__(16) unsigned short Bs[128 * 32];  // [n][k]

    const int t    = threadIdx.x;
    const int lane = t & 63;
    const int w    = t >> 6;
    const int wm   = w >> 1, wn = w & 1;       // wave tile: 32 x 64

    f32x4 acc[2][4] = {};

    const int ar = t >> 2;              // staging row (0..63)
    const int ac = (t & 3) * 8;         // staging k-offset (bf16 elems)

    for (int k0 = 0; k0 < 1024; k0 += 32) {
        uint4 av  = *(const uint4*)(Ab + (long)(m0 + ar) * 1024 + k0 + ac);
        uint4 bv0 = *(const uint4*)(Bb + (long)(n0 + ar) * 1024 + k0 + ac);
        uint4 bv1 = *(const uint4*)(Bb + (long)(n0 + 64 + ar) * 1024 + k0 + ac);
        __syncthreads();                 // prior-iter LDS reads done
        *(uint4*)&As[t * 8]        = av;
        *(uint4*)&Bs[t * 8]        = bv0;
        *(uint4*)&Bs[2048 + t * 8] = bv1;
        __syncthreads();

        const int krow = (lane >> 4) * 8;
        bf16x8 af[2], bf[4];
#pragma unroll
        for (int fi = 0; fi < 2; ++fi)
            af[fi] = *(const bf16x8*)&As[(wm * 32 + fi * 16 + (lane & 15)) * 32 + krow];
#pragma unroll
        for (int fj = 0; fj < 4; ++fj)
            bf[fj] = *(const bf16x8*)&Bs[(wn * 64 + fj * 16 + (lane & 15)) * 32 + krow];
#pragma unroll
        for (int fi = 0; fi < 2; ++fi)
#pragma unroll
            for (int fj = 0; fj < 4; ++fj)
                acc[fi][fj] = __builtin_amdgcn_mfma_f32_16x16x32_bf16(
                    af[fi], bf[fj], acc[fi][fj], 0, 0, 0);
    }

    const int rbase = (lane >> 4) * 4;
    const int cn    = n0 + wn * 64 + (lane & 15);
#pragma unroll
    for (int fi = 0; fi < 2; ++fi) {
        const int mb = m0 + wm * 32 + fi * 16 + rbase;
#pragma unroll
        for (int r = 0; r < 4; ++r) {
            const int m = mb + r;
            if (m < M) {
#pragma unroll
                for (int fj = 0; fj < 4; ++fj) {
                    if constexpr (OUTBF)
                        ((unsigned short*)Cv)[b * sC + (long)m * 1024 + cn + fj * 16]
                            = f2bf(acc[fi][fj][r]);
                    else
                        ((float*)Cv)[b * sC + (long)m * 1024 + cn + fj * 16]
                            = acc[fi][fj][r];
                }
            }
        }
    }
}

// ---------------- projection bf16 MFMA GEMM: C[m][n] = sum_k A[m][k]*B[n][k]
// Tile 64x64, 4 waves (2x2). OM: 0 = f32 only, 1 = dual, 2 = bf16 only.
template <int OM>
__global__ __launch_bounds__(256) void pgemm_k(
    const unsigned short* __restrict__ A, const unsigned short* __restrict__ B,
    const float* __restrict__ bias, float* __restrict__ C,
    unsigned short* __restrict__ Cbf,
    int M, int K, int lda, int ldb, int ldc)
{
    const int m0 = blockIdx.y * 64;
    const int n0 = blockIdx.x * 64;

    __shared__ __align__(16) unsigned short As[64 * 32];
    __shared__ __align__(16) unsigned short Bs[64 * 32];

    const int t    = threadIdx.x;
    const int lane = t & 63;
    const int w    = t >> 6;
    const int wm   = w >> 1, wn = w & 1;   // wave tile: 32 x 32
    const int lm   = lane & 15, lg = lane >> 4;

    const int ar = t >> 2;
    const int ac = (t & 3) * 8;

    f32x4 acc[2][2] = {};

    for (int k0 = 0; k0 < K; k0 += 32) {
        uint4 av = *(const uint4*)(A + (long)(m0 + ar) * lda + k0 + ac);
        uint4 bv = *(const uint4*)(B + (long)(n0 + ar) * ldb + k0 + ac);
        __syncthreads();
        *(uint4*)&As[t * 8] = av;
        *(uint4*)&Bs[t * 8] = bv;
        __syncthreads();

        const int krow = lg * 8 & 24;
        bf16x8 af[2], bf[2];
#pragma unroll
        for (int fi = 0; fi < 2; ++fi)
            af[fi] = *(const bf16x8*)&As[(wm * 32 + fi * 16 + lm) * 32 + krow];
#pragma unroll
        for (int fj = 0; fj < 2; ++fj)
            bf[fj] = *(const bf16x8*)&Bs[(wn * 32 + fj * 16 + lm) * 32 + krow];
#pragma unroll
        for (int fi = 0; fi < 2; ++fi)
#pragma unroll
            for (int fj = 0; fj < 2; ++fj)
                acc[fi][fj] = __builtin_amdgcn_mfma_f32_16x16x32_bf16(
                    af[fi], bf[fj], acc[fi][fj], 0, 0, 0);
    }

    const int rbase = lg * 4;
#pragma unroll
    for (int fi = 0; fi < 2; ++fi) {
        const int mb = m0 + wm * 32 + fi * 16 + rbase;
#pragma unroll
        for (int r = 0; r < 4; ++r) {
            const int m = mb + r;
            if (m < M) {
#pragma unroll
                for (int fj = 0; fj < 2; ++fj) {
                    const int n = n0 + wn * 32 + fj * 16 + lm;
                    float v = acc[fi][fj][r];
                    if (bias) v += bias[n];
                    if constexpr (OM != 2) C[(long)m * ldc + n] = v;
                    if constexpr (OM >= 1) Cbf[(long)m * ldc + n] = f2bf(v);
                }
            }
        }
    }
}

// ---------------- qW kernel: qW[b,(m,h),e] = bf16(scale * q[b,m,h-slice].WkT[e,h-slice])
// M=16 (15 valid), N=1024, K=128. Direct-global fragments (operands L2-hot).
// grid (4, 256): x = 256-col block, y = b*8+h. 4 waves, wave = 64 cols.
__global__ __launch_bounds__(256) void qw_k(
    const unsigned short* __restrict__ qbf, const unsigned short* __restrict__ WkT,
    unsigned short* __restrict__ qW, float scale)
{
    const int z = blockIdx.y;
    const int b = z >> 3, h = z & 7;
    const int w = threadIdx.x >> 6, lane = threadIdx.x & 63;
    const int lm = lane & 15, lg = lane >> 4;
    const int n0w = blockIdx.x * 256 + w * 64;

    const unsigned short* Ar = qbf + (long)(b * 15 + lm) * 1024 + h * 128 + lg * 8;
    const unsigned short* Br = WkT + (long)(n0w + lm) * 1024 + h * 128 + lg * 8;

    bf16x8 af[4];
#pragma unroll
    for (int ks = 0; ks < 4; ++ks) af[ks] = *(const bf16x8*)(Ar + ks * 32);

    f32x4 acc[4] = {};
#pragma unroll
    for (int fj = 0; fj < 4; ++fj) {
#pragma unroll
        for (int ks = 0; ks < 4; ++ks) {
            bf16x8 bf = *(const bf16x8*)(Br + (long)fj * 16 * 1024 + ks * 32);
            acc[fj] = __builtin_amdgcn_mfma_f32_16x16x32_bf16(af[ks], bf, acc[fj], 0, 0, 0);
        }
    }

#pragma unroll
    for (int r = 0; r < 4; ++r) {
        const int m = lg * 4 + r;
        if (m < 15) {
#pragma unroll
            for (int fj = 0; fj < 4; ++fj)
                qW[(long)b * 131072 + (long)(m * 8 + h) * 1024 + n0w + fj * 16 + lm]
                    = f2bf(acc[fj][r] * scale);
        }
    }
}

// ---------------- ctx kernel: ctx_bf[b*15+m][h*128+n] = bf16(ctxf[b,(m,h),:].Wv[h*128+n,:] + bv)
// M=16 (15 valid), N=128, K=1024. grid (256) = (b,h); 4 waves, wave = 32 cols.
__global__ __launch_bounds__(256) void ctx_k(
    const unsigned short* __restrict__ cf, const unsigned short* __restrict__ Wvb,
    const float* __restrict__ bv, unsigned short* __restrict__ ctx)
{
    const int z = blockIdx.x;
    const int b = z >> 3, h = z & 7;
    const int w = threadIdx.x >> 6, lane = threadIdx.x & 63;
    const int lm = lane & 15, lg = lane >> 4;

    const unsigned short* Ar = cf + (long)b * 122880 + (long)(lm * 8 + h) * 1024 + lg * 8;
    const unsigned short* Br = Wvb + (long)(h * 128 + w * 32 + lm) * 1024 + lg * 8;

    f32x4 acc[2] = {};
    for (int k0 = 0; k0 < 1024; k0 += 32) {
        bf16x8 af = *(const bf16x8*)(Ar + k0);
        bf16x8 b0 = *(const bf16x8*)(Br + k0);
        bf16x8 b1 = *(const bf16x8*)(Br + 16 * 1024 + k0);
        acc[0] = __builtin_amdgcn_mfma_f32_16x16x32_bf16(af, b0, acc[0], 0, 0, 0);
        acc[1] = __builtin_amdgcn_mfma_f32_16x16x32_bf16(af, b1, acc[1], 0, 0, 0);
    }

#pragma unroll
    for (int r = 0; r < 4; ++r) {
        const int m = lg * 4 + r;
        if (m < 15) {
#pragma unroll
            for (int fj = 0; fj < 2; ++fj) {
                const int gcol = h * 128 + w * 32 + fj * 16 + lm;
                ctx[(long)(b * 15 + m) * 1024 + gcol] = f2bf(acc[fj][r] + bv[gcol]);
            }
        }
    }
}

// ---------------- fused weight convert: y=0 Wq, 1 Wo, 2 Wv, 3 W1-reshape
__global__ __launch_bounds__(256) void cvtW_k(
    const float* __restrict__ Wq, const float* __restrict__ Wo,
    const float* __restrict__ Wv, const float* __restrict__ W1,
    unsigned short* __restrict__ dWq, unsigned short* __restrict__ dWo,
    unsigned short* __restrict__ dWv, unsigned short* __restrict__ dW1r)
{
    const int which = blockIdx.y;
    const int i = blockIdx.x * 256 + threadIdx.x;   // vec4 index, 262144/matrix
    const float* s;
    unsigned short* d;
    if (which == 3) {
        const int flat = i * 4, n = flat >> 10, k = flat & 1023;
        s = (n < 512) ? W1 + (long)n * 2048 + k : W1 + (long)(n - 512) * 2048 + 1024 + k;
        d = dW1r + flat;
    } else {
        s = (which == 0 ? Wq : which == 1 ? Wo : Wv) + (long)i * 4;
        d = (which == 0 ? dWq : which == 1 ? dWo : dWv) + (long)i * 4;
    }
    float4 v = *(const float4*)s;
    ushort4 o;
    o.x = f2bf(v.x); o.y = f2bf(v.y); o.z = f2bf(v.z); o.w = f2bf(v.w);
    *(ushort4*)d = o;
}

// ---------------- transpose-convert: WkT[e][d] = bf16(Wk[d][e]). grid (16,16).
__global__ __launch_bounds__(256) void cvtT_k(
    const float* __restrict__ src, unsigned short* __restrict__ dst)
{
    const int d0 = blockIdx.y * 64, e0 = blockIdx.x * 64;
    __shared__ unsigned short tile[64][72];
    const int t = threadIdx.x;
    const int r0 = t >> 4, c0 = (t & 15) * 4;
#pragma unroll
    for (int rr = 0; rr < 4; ++rr) {
        const int r = r0 + rr * 16;
        float4 v = *(const float4*)&src[(long)(d0 + r) * 1024 + e0 + c0];
        tile[r][c0 + 0] = f2bf(v.x); tile[r][c0 + 1] = f2bf(v.y);
        tile[r][c0 + 2] = f2bf(v.z); tile[r][c0 + 3] = f2bf(v.w);
    }
    __syncthreads();
#pragma unroll
    for (int rr = 0; rr < 4; ++rr) {
        const int idx = rr * 256 + t;
        const int e = idx >> 4, c4 = (idx & 15) * 4;
        ushort4 o;
        o.x = tile[c4 + 0][e]; o.y = tile[c4 + 1][e];
        o.z = tile[c4 + 2][e]; o.w = tile[c4 + 3][e];
        *(ushort4*)&dst[(long)(e0 + e) * 1024 + d0 + c4] = o;
    }
}

// ---------------- fused convert: v_bf[b][l][e] and v_bfT[b][e][l] from fp32
__global__ __launch_bounds__(256) void cvt_k(
    const float* __restrict__ vf, unsigned short* __restrict__ vbf,
    unsigned short* __restrict__ vbfT)
{
    const int b  = blockIdx.z;
    const int e0 = blockIdx.x * 64;
    const int l0 = blockIdx.y * 64;
    const float* src = vf + (long)b * 4194304;   // batch stride = T*L*D
    __shared__ unsigned short tile[64][72];
    const int t = threadIdx.x;
    const int r0 = t >> 4, c0 = (t & 15) * 4;
#pragma unroll
    for (int rr = 0; rr < 4; ++rr) {
        const int r = r0 + rr * 16;
        float4 v = *(const float4*)&src[(long)(l0 + r) * 1024 + e0 + c0];
        ushort4 o;
        o.x = f2bf(v.x); o.y = f2bf(v.y); o.z = f2bf(v.z); o.w = f2bf(v.w);
        tile[r][c0 + 0] = o.x; tile[r][c0 + 1] = o.y;
        tile[r][c0 + 2] = o.z; tile[r][c0 + 3] = o.w;
        *(ushort4*)&vbf[(long)b * 1048576 + (long)(l0 + r) * 1024 + e0 + c0] = o;
    }
    __syncthreads();
#pragma unroll
    for (int rr = 0; rr < 4; ++rr) {
        const int idx = rr * 256 + t;
        const int e   = idx >> 4;
        const int c4  = (idx & 15) * 4;
        ushort4 o;
        o.x = tile[c4 + 0][e]; o.y = tile[c4 + 1][e];
        o.z = tile[c4 + 2][e]; o.w = tile[c4 + 3][e];
        *(ushort4*)&vbfT[(long)b * 1048576 + (long)(e0 + e) * 1024 + l0 + c4] = o;
    }
}

// ---------------- query_bf[b,n,d] = bf16(emb[..] + bboxes.Wb[d,:] + bb[d])
__global__ __launch_bounds__(256) void build_query_k(
    const int* __restrict__ nodes, const float* __restrict__ bboxes,
    const float* __restrict__ emb, const float* __restrict__ Wb,
    const float* __restrict__ bb, unsigned short* __restrict__ qbf)
{
    const int blk = blockIdx.x;
    const int node = nodes[blk];
    const int idx = node < 0 ? 0 : node;
    const float4 bx = *(const float4*)&bboxes[blk * 4];
    const float* er = emb + (long)idx * 1024;
    for (int d = threadIdx.x; d < 1024; d += 256) {
        const float4 w = *(const float4*)&Wb[d * 4];
        qbf[(long)blk * 1024 + d] = f2bf(
            er[d] + bb[d] + bx.x * w.x + bx.y * w.y + bx.z * w.z + bx.w * w.w);
    }
}

// ---------------- row softmax over 1024; fp32 in, bf16 out (padded 128 rows/b)
__global__ __launch_bounds__(256) void softmax_k(
    const float* __restrict__ sc, unsigned short* __restrict__ attn)
{
    __shared__ float red[4];
    const int blk = blockIdx.x;              // b*120 + r
    const int b = blk / 120, r = blk % 120;
    const float* p = sc + (long)blk * 1024;
    const int t = threadIdx.x;
    float4 v = *(const float4*)&p[t * 4];

    float m = fmaxf(fmaxf(v.x, v.y), fmaxf(v.z, v.w));
#pragma unroll
    for (int o = 32; o; o >>= 1) m = fmaxf(m, __shfl_xor(m, o));
    if ((t & 63) == 0) red[t >> 6] = m;
    __syncthreads();
    m = fmaxf(fmaxf(red[0], red[1]), fmaxf(red[2], red[3]));
    __syncthreads();

    v.x = __expf(v.x - m); v.y = __expf(v.y - m);
    v.z = __expf(v.z - m); v.w = __expf(v.w - m);
    float s = v.x + v.y + v.z + v.w;
#pragma unroll
    for (int o = 32; o; o >>= 1) s += __shfl_xor(s, o);
    if ((t & 63) == 0) red[t >> 6] = s;
    __syncthreads();
    s = red[0] + red[1] + red[2] + red[3];
    const float inv = 1.0f / s;
    ushort4 o;
    o.x = f2bf(v.x * inv); o.y = f2bf(v.y * inv);
    o.z = f2bf(v.z * inv); o.w = f2bf(v.w * inv);
    *(ushort4*)&attn[(long)(b * 128 + r) * 1024 + t * 4] = o;
}

// ---------------- edge head: one block per (b, i). thread = (j, c).
// hh: [480][1024], cols 0..511 = hi (no bias), 512..1023 = hj. b1 added here.
__global__ __launch_bounds__(320) void edge_k(
    const float* __restrict__ hh, const float* __restrict__ b1,
    const float* __restrict__ W2, const float* __restrict__ b2,
    float* __restrict__ out)
{
    const int b = blockIdx.x, i = blockIdx.y;
    const int t = threadIdx.x;
    __shared__ float hiS[256];
    __shared__ float b1S[256];
    __shared__ float hjS[15][257];
    __shared__ float w2S[18][257];
    const int j = t / 18, c = t % 18;
    float acc = 0.0f;

    for (int u0 = 0; u0 < 512; u0 += 256) {
        __syncthreads();
        if (t < 64) {
            float4 v = *(const float4*)&hh[(long)(b * 15 + i) * 1024 + u0 + t * 4];
            hiS[t * 4 + 0] = v.x; hiS[t * 4 + 1] = v.y;
            hiS[t * 4 + 2] = v.z; hiS[t * 4 + 3] = v.w;
        } else if (t < 128) {
            const int tt = t - 64;
            float4 v = *(const float4*)&b1[u0 + tt * 4];
            b1S[tt * 4 + 0] = v.x; b1S[tt * 4 + 1] = v.y;
            b1S[tt * 4 + 2] = v.z; b1S[tt * 4 + 3] = v.w;
        }
        for (int x = t; x < 960; x += 320) {
            const int r = x >> 6, cc = (x & 63) * 4;
            float4 v = *(const float4*)&hh[(long)(b * 15 + r) * 1024 + 512 + u0 + cc];
            hjS[r][cc + 0] = v.x; hjS[r][cc + 1] = v.y;
            hjS[r][cc + 2] = v.z; hjS[r][cc + 3] = v.w;
        }
        for (int x = t; x < 1152; x += 320) {
            const int r = x >> 6, cc = (x & 63) * 4;
            float4 v = *(const float4*)&W2[(long)r * 512 + u0 + cc];
            w2S[r][cc + 0] = v.x; w2S[r][cc + 1] = v.y;
            w2S[r][cc + 2] = v.z; w2S[r][cc + 3] = v.w;
        }
        __syncthreads();
        if (t < 270) {
            for (int u = 0; u < 256; ++u) {
                float p = hiS[u] + hjS[j][u] + b1S[u];
                p = p > 0.0f ? p : 0.0f;
                acc += p * w2S[c][u];
            }
        }
    }
    if (t < 270)
        out[((long)(b * 15 + i) * 15 + j) * 18 + c] = acc + b2[c];
}

// ---------------- energy stage 1
__global__ __launch_bounds__(256) void energy1_k(
    const float* __restrict__ enr, const int* __restrict__ nodes,
    float* __restrict__ gfeat)
{
    const int b = blockIdx.y;
    const int e = blockIdx.x * 256 + threadIdx.x;
    int cnt = 0;
#pragma unroll
    for (int n = 0; n < 15; ++n) cnt += (nodes[b * 15 + n] != -1) ? 1 : 0;
    const float inv_valid = 1.0f / fmaxf((float)cnt, 1.0f);
    float s = 0.0f;
#pragma unroll
    for (int n = 0; n < 15; ++n) {
        const bool ok = nodes[b * 15 + n] != -1;
        s += ok ? enr[(long)(b * 15 + n) * 1024 + e] : 0.0f;
    }
    gfeat[b * 1024 + e] = s * inv_valid;
}

// ---------------- energy stage 2
__global__ __launch_bounds__(256) void energy2_k(
    const float* __restrict__ gfeat, const float* __restrict__ Wh1,
    const float* __restrict__ bh1, const float* __restrict__ Wh2,
    float* __restrict__ hidr)
{
    const int b  = blockIdx.y;
    const int u0 = blockIdx.x * 16;
    const int t = threadIdx.x;
    __shared__ float gf[1024];
    {
        float4 v = *(const float4*)&gfeat[b * 1024 + t * 4];
        gf[t * 4 + 0] = v.x; gf[t * 4 + 1] = v.y;
        gf[t * 4 + 2] = v.z; gf[t * 4 + 3] = v.w;
    }
    __syncthreads();
    const int wave = t >> 6, lane = t & 63;
#pragma unroll
    for (int r = 0; r < 4; ++r) {
        const int u = u0 + wave * 4 + r;
        float s = 0.0f;
#pragma unroll
        for (int e0 = 0; e0 < 1024; e0 += 64)
            s += gf[e0 + lane] * Wh1[(long)u * 1024 + e0 + lane];
#pragma unroll
        for (int o = 32; o; o >>= 1) s += __shfl_xor(s, o);
        if (lane == 0)
            hidr[b * 256 + u] = fmaxf(s + bh1[u], 0.0f) * Wh2[u];
    }
}

// ---------------- energy stage 3
__global__ __launch_bounds__(256) void energy3_k(
    const float* __restrict__ hidr, const float* __restrict__ bh2,
    float* __restrict__ out)
{
    const int b = blockIdx.x;
    const int t = threadIdx.x;
    __shared__ float red[4];
    float v = hidr[b * 256 + t];
#pragma unroll
    for (int o = 32; o; o >>= 1) v += __shfl_xor(v, o);
    if ((t & 63) == 0) red[t >> 6] = v;
    __syncthreads();
    if (t == 0) out[129600 + b] = red[0] + red[1] + red[2] + red[3] + bh2[0];
}

// ---------------------------------------------------------------------------
extern "C" void kernel_launch(void* const* d_in, const int* in_sizes, int n_in,
                              void* d_out, int out_size, void* d_ws, size_t ws_size,
                              hipStream_t stream)
{
    const float* visual = (const float*)d_in[0];
    const int*   nodes  = (const int*)  d_in[1];
    const float* bboxes = (const float*)d_in[2];
    const float* emb    = (const float*)d_in[3];
    const float* Wb     = (const float*)d_in[4];
    const float* bb     = (const float*)d_in[5];
    const float* Wq     = (const float*)d_in[6];
    const float* bq     = (const float*)d_in[7];
    const float* Wk     = (const float*)d_in[8];
    /* bk (d_in[9]) cancels in softmax */
    const float* Wv     = (const float*)d_in[10];
    const float* bv     = (const float*)d_in[11];
    const float* Wo     = (const float*)d_in[12];
    const float* bo     = (const float*)d_in[13];
    const float* W1     = (const float*)d_in[14];
    const float* b1     = (const float*)d_in[15];
    const float* W2     = (const float*)d_in[16];
    const float* b2     = (const float*)d_in[17];
    const float* Wh1    = (const float*)d_in[18];
    const float* bh1    = (const float*)d_in[19];
    const float* Wh2    = (const float*)d_in[20];
    const float* bh2    = (const float*)d_in[21];

    float* out = (float*)d_out;
    float* ws  = (float*)d_ws;

    // workspace layout (offsets in fp32 words)
    unsigned short* query_bf = (unsigned short*)(ws);            // 512x1024 bf16
    unsigned short* q_bf     = (unsigned short*)(ws + 131072);   // 512x1024 bf16
    float* scores = ws + 262144;              // 32*120*1024 f32
    unsigned short* ctxf_bf  = (unsigned short*)(ws + 4194304);  // 32*120*1024 bf16
    unsigned short* ctx_bf   = (unsigned short*)(ws + 6160384);  // 512x1024 bf16
    float* enr    = ws + 6422528;             // 480*1024 f32
    unsigned short* enr_bf   = (unsigned short*)(ws + 6914048);  // 512x1024 bf16
    float* hh     = ws + 7176192;             // 480*1024 f32 (hi|hj)
    unsigned short* Wq_bf  = (unsigned short*)(ws + 7667712);    // 1024x1024 bf16
    unsigned short* Wo_bf  = (unsigned short*)(ws + 8192000);    // 1024x1024 bf16
    unsigned short* Wv_bf  = (unsigned short*)(ws + 8716288);    // 1024x1024 bf16
    unsigned short* W1r_bf = (unsigned short*)(ws + 9240576);    // 1024x1024 bf16
    unsigned short* WkT_bf = (unsigned short*)(ws + 9764864);    // 1024x1024 bf16
    unsigned short* qW_bf   = (unsigned short*)(ws + 10289152);  // 32*128*1024 bf16
    unsigned short* attn_bf = (unsigned short*)(ws + 12386304);  // 32*128*1024 bf16
    unsigned short* v_bf    = (unsigned short*)(ws + 14483456);  // 32*1024*1024 bf16
    unsigned short* v_bfT   = (unsigned short*)(ws + 31260672);  // 32*1024*1024 bf16
    float* gfeat  = ws + 48037888;            // 32*1024
    float* hidr   = ws + 48070656;            // 32*256

    const float inv_sqrt_hd = 0.08838834764831845f;  // 1/sqrt(128)
    const float* v_f = visual + 3 * 1048576;         // frame T-1; batch stride 4*1048576

    // 1) input conversions (independent)
    build_query_k<<<480, 256, 0, stream>>>(nodes, bboxes, emb, Wb, bb, query_bf);
    cvt_k<<<dim3(16, 16, 32), 256, 0, stream>>>(v_f, v_bf, v_bfT);
    cvtW_k<<<dim3(1024, 4), 256, 0, stream>>>(Wq, Wo, Wv, W1, Wq_bf, Wo_bf, Wv_bf, W1r_bf);
    cvtT_k<<<dim3(16, 16), 256, 0, stream>>>(Wk, WkT_bf);

    // 2) q_bf = query_bf @ Wq_bf^T + bq   (MFMA, bf16-only out)
    pgemm_k<2><<<dim3(16, 8), 256, 0, stream>>>(
        query_bf, Wq_bf, bq, nullptr, q_bf, 480, 1024, 1024, 1024, 1024);

    // 3) qW_bf = (q_bf @ WkT_bf^T) * inv_sqrt_hd   (MFMA, batch (b,h))
    qw_k<<<dim3(4, 256), 256, 0, stream>>>(q_bf, WkT_bf, qW_bf, inv_sqrt_hd);

    // 4) scores[b] = qW_bf[b] @ v_bf[b]^T   (MFMA, M=120 pad 128)
    bfgemm_k<false><<<dim3(8, 2, 32), 256, 0, stream>>>(
        qW_bf, v_bf, scores, 120, 131072, 1048576, 122880);

    // 5) softmax over l -> bf16 attn
    softmax_k<<<3840, 256, 0, stream>>>(scores, attn_bf);

    // 6) ctxf_bf[b] = attn[b] @ v_bfT[b]^T  (MFMA, bf16 out)
    bfgemm_k<true><<<dim3(8, 2, 32), 256, 0, stream>>>(
        attn_bf, v_bfT, ctxf_bf, 120, 131072, 1048576, 122880);

    // 7) ctx_bf = ctxf_bf @ Wv^T + bv      (MFMA, batch (b,h))
    ctx_k<<<256, 256, 0, stream>>>(ctxf_bf, Wv_bf, bv, ctx_bf);

    // 8) enr = ctx_bf @ Wo_bf^T + bo       (MFMA, dual out)
    pgemm_k<1><<<dim3(16, 8), 256, 0, stream>>>(
        ctx_bf, Wo_bf, bo, enr, enr_bf, 480, 1024, 1024, 1024, 1024);

    // 9) hh = enr_bf @ W1r_bf^T            (MFMA; cols 0..511 hi, 512..1023 hj)
    pgemm_k<0><<<dim3(16, 8), 256, 0, stream>>>(
        enr_bf, W1r_bf, nullptr, hh, nullptr, 480, 1024, 1024, 1024, 1024);

    // 10) edge logits -> out[0 .. 129600)   (b1 applied inside)
    edge_k<<<dim3(32, 15), 320, 0, stream>>>(hh, b1, W2, b2, out);

    // 11) energy -> out[129600 .. 129632)
    energy1_k<<<dim3(4, 32), 256, 0, stream>>>(enr, nodes, gfeat);
    energy2_k<<<dim3(16, 32), 256, 0, stream>>>(gfeat, Wh1, bh1, Wh2, hidr);
    energy3_k<<<32, 256, 0, stream>>>(hidr, bh2, out);
}

// Round 12
// 238.450 us; speedup vs baseline: 2.7626x; 1.0297x over previous
//
#include <hip/hip_runtime.h>

// ---------------------------------------------------------------------------
// RelationalTransformer: B=32 T=4 L=1024 D=1024 H=8 Hd=128 N=15
// out = edge_logits (32*15*15*18 = 129600) ++ energy (32)   [fp32]
//
// R12: (a) bfgemm/pgemm staging -> __builtin_amdgcn_global_load_lds width=16
// (m93->m97 ladder step; LDS content byte-identical to reg-staged v1);
// (b) build_query+cvtW+cvtT fused into uber_cvt_k; energy1 folded into
// energy2. 16 -> 13 dispatches. All changes bit-exact vs R11.
// ---------------------------------------------------------------------------

typedef __attribute__((ext_vector_type(8))) short bf16x8;   // 8 bf16 in 4 VGPRs
typedef __attribute__((ext_vector_type(4))) float f32x4;

__device__ __forceinline__ unsigned short f2bf(float f) {   // RNE float->bf16
    unsigned int u = __float_as_uint(f);
    u = u + 0x7FFFu + ((u >> 16) & 1u);
    return (unsigned short)(u >> 16);
}

// async global->LDS, 16B per lane, dest = wave-uniform base + lane*16
__device__ __forceinline__ void gload_lds16(const void* g, void* l) {
    __builtin_amdgcn_global_load_lds(
        (const __attribute__((address_space(1))) void*)g,
        (__attribute__((address_space(3))) void*)l,
        16, 0, 0);
}

// ---------------- bf16 MFMA GEMM (64x128 tile, 4 waves): C = A @ B^T
// v5: global_load_lds staging. LDS layout/content identical to v1.
template <bool OUTBF>
__global__ __launch_bounds__(256) void bfgemm_k(
    const unsigned short* __restrict__ A, const unsigned short* __restrict__ B,
    void* __restrict__ Cv, int M, long sA, long sB, long sC)
{
    const int b  = blockIdx.z;
    const int m0 = blockIdx.y * 64;
    const int n0 = blockIdx.x * 128;
    const unsigned short* Ab = A + b * sA;
    const unsigned short* Bb = B + b * sB;

    __shared__ __align__(16) unsigned short As[64 * 32];   // [m][k]
    __shared__ __align__(16) unsigned short Bs[128 * 32];  // [n][k]

    const int t    = threadIdx.x;
    const int lane = t & 63;
    const int w    = t >> 6;
    const int wm   = w >> 1, wn = w & 1;       // wave tile: 32 x 64

    f32x4 acc[2][4] = {};

    const int ar = t >> 2;              // staging row (0..63)
    const int ac = (t & 3) * 8;         // staging k-offset (bf16 elems)

    // wave-uniform LDS bases; lane lands at base + lane*16B == old As[t*8]
    unsigned short* AsW  = As + w * 512;
    unsigned short* BsW0 = Bs + w * 512;
    unsigned short* BsW1 = Bs + 2048 + w * 512;
    const unsigned short* ga  = Ab + (long)(m0 + ar) * 1024 + ac;
    const unsigned short* gb0 = Bb + (long)(n0 + ar) * 1024 + ac;
    const unsigned short* gb1 = Bb + (long)(n0 + 64 + ar) * 1024 + ac;

    for (int k0 = 0; k0 < 1024; k0 += 32) {
        __syncthreads();                 // prior-iter ds_reads done
        gload_lds16(ga  + k0, AsW);
        gload_lds16(gb0 + k0, BsW0);
        gload_lds16(gb1 + k0, BsW1);
        __syncthreads();                 // drains vmcnt(0): LDS tile valid

        const int krow = (lane >> 4) * 8;
        bf16x8 af[2], bf[4];
#pragma unroll
        for (int fi = 0; fi < 2; ++fi)
            af[fi] = *(const bf16x8*)&As[(wm * 32 + fi * 16 + (lane & 15)) * 32 + krow];
#pragma unroll
        for (int fj = 0; fj < 4; ++fj)
            bf[fj] = *(const bf16x8*)&Bs[(wn * 64 + fj * 16 + (lane & 15)) * 32 + krow];
#pragma unroll
        for (int fi = 0; fi < 2; ++fi)
#pragma unroll
            for (int fj = 0; fj < 4; ++fj)
                acc[fi][fj] = __builtin_amdgcn_mfma_f32_16x16x32_bf16(
                    af[fi], bf[fj], acc[fi][fj], 0, 0, 0);
    }

    const int rbase = (lane >> 4) * 4;
    const int cn    = n0 + wn * 64 + (lane & 15);
#pragma unroll
    for (int fi = 0; fi < 2; ++fi) {
        const int mb = m0 + wm * 32 + fi * 16 + rbase;
#pragma unroll
        for (int r = 0; r < 4; ++r) {
            const int m = mb + r;
            if (m < M) {
#pragma unroll
                for (int fj = 0; fj < 4; ++fj) {
                    if constexpr (OUTBF)
                        ((unsigned short*)Cv)[b * sC + (long)m * 1024 + cn + fj * 16]
                            = f2bf(acc[fi][fj][r]);
                    else
                        ((float*)Cv)[b * sC + (long)m * 1024 + cn + fj * 16]
                            = acc[fi][fj][r];
                }
            }
        }
    }
}

// ---------------- projection bf16 MFMA GEMM (64x64 tile, gload_lds staging)
// OM: 0 = f32 only, 1 = dual, 2 = bf16 only.
template <int OM>
__global__ __launch_bounds__(256) void pgemm_k(
    const unsigned short* __restrict__ A, const unsigned short* __restrict__ B,
    const float* __restrict__ bias, float* __restrict__ C,
    unsigned short* __restrict__ Cbf,
    int M, int K, int lda, int ldb, int ldc)
{
    const int m0 = blockIdx.y * 64;
    const int n0 = blockIdx.x * 64;

    __shared__ __align__(16) unsigned short As[64 * 32];
    __shared__ __align__(16) unsigned short Bs[64 * 32];

    const int t    = threadIdx.x;
    const int lane = t & 63;
    const int w    = t >> 6;
    const int wm   = w >> 1, wn = w & 1;   // wave tile: 32 x 32
    const int lm   = lane & 15, lg = lane >> 4;

    const int ar = t >> 2;
    const int ac = (t & 3) * 8;

    f32x4 acc[2][2] = {};

    unsigned short* AsW = As + w * 512;
    unsigned short* BsW = Bs + w * 512;
    const unsigned short* ga = A + (long)(m0 + ar) * lda + ac;
    const unsigned short* gb = B + (long)(n0 + ar) * ldb + ac;

    for (int k0 = 0; k0 < K; k0 += 32) {
        __syncthreads();
        gload_lds16(ga + k0, AsW);
        gload_lds16(gb + k0, BsW);
        __syncthreads();

        const int krow = lg * 8 & 24;
        bf16x8 af[2], bf[2];
#pragma unroll
        for (int fi = 0; fi < 2; ++fi)
            af[fi] = *(const bf16x8*)&As[(wm * 32 + fi * 16 + lm) * 32 + krow];
#pragma unroll
        for (int fj = 0; fj < 2; ++fj)
            bf[fj] = *(const bf16x8*)&Bs[(wn * 32 + fj * 16 + lm) * 32 + krow];
#pragma unroll
        for (int fi = 0; fi < 2; ++fi)
#pragma unroll
            for (int fj = 0; fj < 2; ++fj)
                acc[fi][fj] = __builtin_amdgcn_mfma_f32_16x16x32_bf16(
                    af[fi], bf[fj], acc[fi][fj], 0, 0, 0);
    }

    const int rbase = lg * 4;
#pragma unroll
    for (int fi = 0; fi < 2; ++fi) {
        const int mb = m0 + wm * 32 + fi * 16 + rbase;
#pragma unroll
        for (int r = 0; r < 4; ++r) {
            const int m = mb + r;
            if (m < M) {
#pragma unroll
                for (int fj = 0; fj < 2; ++fj) {
                    const int n = n0 + wn * 32 + fj * 16 + lm;
                    float v = acc[fi][fj][r];
                    if (bias) v += bias[n];
                    if constexpr (OM != 2) C[(long)m * ldc + n] = v;
                    if constexpr (OM >= 1) Cbf[(long)m * ldc + n] = f2bf(v);
                }
            }
        }
    }
}

// ---------------- qW kernel: qW[b,(m,h),e] = bf16(scale * q.WkT)  (unchanged)
__global__ __launch_bounds__(256) void qw_k(
    const unsigned short* __restrict__ qbf, const unsigned short* __restrict__ WkT,
    unsigned short* __restrict__ qW, float scale)
{
    const int z = blockIdx.y;
    const int b = z >> 3, h = z & 7;
    const int w = threadIdx.x >> 6, lane = threadIdx.x & 63;
    const int lm = lane & 15, lg = lane >> 4;
    const int n0w = blockIdx.x * 256 + w * 64;

    const unsigned short* Ar = qbf + (long)(b * 15 + lm) * 1024 + h * 128 + lg * 8;
    const unsigned short* Br = WkT + (long)(n0w + lm) * 1024 + h * 128 + lg * 8;

    bf16x8 af[4];
#pragma unroll
    for (int ks = 0; ks < 4; ++ks) af[ks] = *(const bf16x8*)(Ar + ks * 32);

    f32x4 acc[4] = {};
#pragma unroll
    for (int fj = 0; fj < 4; ++fj) {
#pragma unroll
        for (int ks = 0; ks < 4; ++ks) {
            bf16x8 bf = *(const bf16x8*)(Br + (long)fj * 16 * 1024 + ks * 32);
            acc[fj] = __builtin_amdgcn_mfma_f32_16x16x32_bf16(af[ks], bf, acc[fj], 0, 0, 0);
        }
    }

#pragma unroll
    for (int r = 0; r < 4; ++r) {
        const int m = lg * 4 + r;
        if (m < 15) {
#pragma unroll
            for (int fj = 0; fj < 4; ++fj)
                qW[(long)b * 131072 + (long)(m * 8 + h) * 1024 + n0w + fj * 16 + lm]
                    = f2bf(acc[fj][r] * scale);
        }
    }
}

// ---------------- ctx kernel (unchanged)
__global__ __launch_bounds__(256) void ctx_k(
    const unsigned short* __restrict__ cf, const unsigned short* __restrict__ Wvb,
    const float* __restrict__ bv, unsigned short* __restrict__ ctx)
{
    const int z = blockIdx.x;
    const int b = z >> 3, h = z & 7;
    const int w = threadIdx.x >> 6, lane = threadIdx.x & 63;
    const int lm = lane & 15, lg = lane >> 4;

    const unsigned short* Ar = cf + (long)b * 122880 + (long)(lm * 8 + h) * 1024 + lg * 8;
    const unsigned short* Br = Wvb + (long)(h * 128 + w * 32 + lm) * 1024 + lg * 8;

    f32x4 acc[2] = {};
    for (int k0 = 0; k0 < 1024; k0 += 32) {
        bf16x8 af = *(const bf16x8*)(Ar + k0);
        bf16x8 b0 = *(const bf16x8*)(Br + k0);
        bf16x8 b1 = *(const bf16x8*)(Br + 16 * 1024 + k0);
        acc[0] = __builtin_amdgcn_mfma_f32_16x16x32_bf16(af, b0, acc[0], 0, 0, 0);
        acc[1] = __builtin_amdgcn_mfma_f32_16x16x32_bf16(af, b1, acc[1], 0, 0, 0);
    }

#pragma unroll
    for (int r = 0; r < 4; ++r) {
        const int m = lg * 4 + r;
        if (m < 15) {
#pragma unroll
            for (int fj = 0; fj < 2; ++fj) {
                const int gcol = h * 128 + w * 32 + fj * 16 + lm;
                ctx[(long)(b * 15 + m) * 1024 + gcol] = f2bf(acc[fj][r] + bv[gcol]);
            }
        }
    }
}

// ---------------- uber conversion kernel: fuses
//   blocks [0,4096):    cvtW (which = bid>>10: Wq, Wo, Wv, W1-reshape)
//   blocks [4096,4352): cvtT (Wk transpose -> WkT)
//   blocks [4352,4832): build_query (bf16)
__global__ __launch_bounds__(256) void uber_cvt_k(
    const int* __restrict__ nodes, const float* __restrict__ bboxes,
    const float* __restrict__ emb, const float* __restrict__ Wb,
    const float* __restrict__ bb, unsigned short* __restrict__ qbf,
    const float* __restrict__ Wq, const float* __restrict__ Wo,
    const float* __restrict__ Wv, const float* __restrict__ W1,
    const float* __restrict__ Wk,
    unsigned short* __restrict__ dWq, unsigned short* __restrict__ dWo,
    unsigned short* __restrict__ dWv, unsigned short* __restrict__ dW1r,
    unsigned short* __restrict__ dWkT)
{
    __shared__ unsigned short tile[64][72];
    const int bid = blockIdx.x;
    const int t = threadIdx.x;

    if (bid < 4096) {                       // elementwise weight converts
        const int which = bid >> 10;
        const int i = (bid & 1023) * 256 + t;
        const float* s;
        unsigned short* d;
        if (which == 3) {
            const int flat = i * 4, n = flat >> 10, k = flat & 1023;
            s = (n < 512) ? W1 + (long)n * 2048 + k
                          : W1 + (long)(n - 512) * 2048 + 1024 + k;
            d = dW1r + flat;
        } else {
            s = (which == 0 ? Wq : which == 1 ? Wo : Wv) + (long)i * 4;
            d = (which == 0 ? dWq : which == 1 ? dWo : dWv) + (long)i * 4;
        }
        float4 v = *(const float4*)s;
        ushort4 o;
        o.x = f2bf(v.x); o.y = f2bf(v.y); o.z = f2bf(v.z); o.w = f2bf(v.w);
        *(ushort4*)d = o;
    } else if (bid < 4352) {                // Wk transpose-convert
        const int tl = bid - 4096;
        const int d0 = (tl >> 4) * 64, e0 = (tl & 15) * 64;
        const int r0 = t >> 4, c0 = (t & 15) * 4;
#pragma unroll
        for (int rr = 0; rr < 4; ++rr) {
            const int r = r0 + rr * 16;
            float4 v = *(const float4*)&Wk[(long)(d0 + r) * 1024 + e0 + c0];
            tile[r][c0 + 0] = f2bf(v.x); tile[r][c0 + 1] = f2bf(v.y);
            tile[r][c0 + 2] = f2bf(v.z); tile[r][c0 + 3] = f2bf(v.w);
        }
        __syncthreads();
#pragma unroll
        for (int rr = 0; rr < 4; ++rr) {
            const int idx = rr * 256 + t;
            const int e = idx >> 4, c4 = (idx & 15) * 4;
            ushort4 o;
            o.x = tile[c4 + 0][e]; o.y = tile[c4 + 1][e];
            o.z = tile[c4 + 2][e]; o.w = tile[c4 + 3][e];
            *(ushort4*)&dWkT[(long)(e0 + e) * 1024 + d0 + c4] = o;
        }
    } else {                                // build query (bf16)
        const int blk = bid - 4352;
        const int node = nodes[blk];
        const int idx = node < 0 ? 0 : node;
        const float4 bx = *(const float4*)&bboxes[blk * 4];
        const float* er = emb + (long)idx * 1024;
        for (int d = t; d < 1024; d += 256) {
            const float4 w = *(const float4*)&Wb[d * 4];
            qbf[(long)blk * 1024 + d] = f2bf(
                er[d] + bb[d] + bx.x * w.x + bx.y * w.y + bx.z * w.z + bx.w * w.w);
        }
    }
}

// ---------------- fused convert: v_bf[b][l][e] and v_bfT[b][e][l] from fp32
__global__ __launch_bounds__(256) void cvt_k(
    const float* __restrict__ vf, unsigned short* __restrict__ vbf,
    unsigned short* __restrict__ vbfT)
{
    const int b  = blockIdx.z;
    const int e0 = blockIdx.x * 64;
    const int l0 = blockIdx.y * 64;
    const float* src = vf + (long)b * 4194304;   // batch stride = T*L*D
    __shared__ unsigned short tile[64][72];
    const int t = threadIdx.x;
    const int r0 = t >> 4, c0 = (t & 15) * 4;
#pragma unroll
    for (int rr = 0; rr < 4; ++rr) {
        const int r = r0 + rr * 16;
        float4 v = *(const float4*)&src[(long)(l0 + r) * 1024 + e0 + c0];
        ushort4 o;
        o.x = f2bf(v.x); o.y = f2bf(v.y); o.z = f2bf(v.z); o.w = f2bf(v.w);
        tile[r][c0 + 0] = o.x; tile[r][c0 + 1] = o.y;
        tile[r][c0 + 2] = o.z; tile[r][c0 + 3] = o.w;
        *(ushort4*)&vbf[(long)b * 1048576 + (long)(l0 + r) * 1024 + e0 + c0] = o;
    }
    __syncthreads();
#pragma unroll
    for (int rr = 0; rr < 4; ++rr) {
        const int idx = rr * 256 + t;
        const int e   = idx >> 4;
        const int c4  = (idx & 15) * 4;
        ushort4 o;
        o.x = tile[c4 + 0][e]; o.y = tile[c4 + 1][e];
        o.z = tile[c4 + 2][e]; o.w = tile[c4 + 3][e];
        *(ushort4*)&vbfT[(long)b * 1048576 + (long)(e0 + e) * 1024 + l0 + c4] = o;
    }
}

// ---------------- row softmax over 1024; fp32 in, bf16 out (padded 128 rows/b)
__global__ __launch_bounds__(256) void softmax_k(
    const float* __restrict__ sc, unsigned short* __restrict__ attn)
{
    __shared__ float red[4];
    const int blk = blockIdx.x;              // b*120 + r
    const int b = blk / 120, r = blk % 120;
    const float* p = sc + (long)blk * 1024;
    const int t = threadIdx.x;
    float4 v = *(const float4*)&p[t * 4];

    float m = fmaxf(fmaxf(v.x, v.y), fmaxf(v.z, v.w));
#pragma unroll
    for (int o = 32; o; o >>= 1) m = fmaxf(m, __shfl_xor(m, o));
    if ((t & 63) == 0) red[t >> 6] = m;
    __syncthreads();
    m = fmaxf(fmaxf(red[0], red[1]), fmaxf(red[2], red[3]));
    __syncthreads();

    v.x = __expf(v.x - m); v.y = __expf(v.y - m);
    v.z = __expf(v.z - m); v.w = __expf(v.w - m);
    float s = v.x + v.y + v.z + v.w;
#pragma unroll
    for (int o = 32; o; o >>= 1) s += __shfl_xor(s, o);
    if ((t & 63) == 0) red[t >> 6] = s;
    __syncthreads();
    s = red[0] + red[1] + red[2] + red[3];
    const float inv = 1.0f / s;
    ushort4 o;
    o.x = f2bf(v.x * inv); o.y = f2bf(v.y * inv);
    o.z = f2bf(v.z * inv); o.w = f2bf(v.w * inv);
    *(ushort4*)&attn[(long)(b * 128 + r) * 1024 + t * 4] = o;
}

// ---------------- edge head: one block per (b, i). thread = (j, c).
__global__ __launch_bounds__(320) void edge_k(
    const float* __restrict__ hh, const float* __restrict__ b1,
    const float* __restrict__ W2, const float* __restrict__ b2,
    float* __restrict__ out)
{
    const int b = blockIdx.x, i = blockIdx.y;
    const int t = threadIdx.x;
    __shared__ float hiS[256];
    __shared__ float b1S[256];
    __shared__ float hjS[15][257];
    __shared__ float w2S[18][257];
    const int j = t / 18, c = t % 18;
    float acc = 0.0f;

    for (int u0 = 0; u0 < 512; u0 += 256) {
        __syncthreads();
        if (t < 64) {
            float4 v = *(const float4*)&hh[(long)(b * 15 + i) * 1024 + u0 + t * 4];
            hiS[t * 4 + 0] = v.x; hiS[t * 4 + 1] = v.y;
            hiS[t * 4 + 2] = v.z; hiS[t * 4 + 3] = v.w;
        } else if (t < 128) {
            const int tt = t - 64;
            float4 v = *(const float4*)&b1[u0 + tt * 4];
            b1S[tt * 4 + 0] = v.x; b1S[tt * 4 + 1] = v.y;
            b1S[tt * 4 + 2] = v.z; b1S[tt * 4 + 3] = v.w;
        }
        for (int x = t; x < 960; x += 320) {
            const int r = x >> 6, cc = (x & 63) * 4;
            float4 v = *(const float4*)&hh[(long)(b * 15 + r) * 1024 + 512 + u0 + cc];
            hjS[r][cc + 0] = v.x; hjS[r][cc + 1] = v.y;
            hjS[r][cc + 2] = v.z; hjS[r][cc + 3] = v.w;
        }
        for (int x = t; x < 1152; x += 320) {
            const int r = x >> 6, cc = (x & 63) * 4;
            float4 v = *(const float4*)&W2[(long)r * 512 + u0 + cc];
            w2S[r][cc + 0] = v.x; w2S[r][cc + 1] = v.y;
            w2S[r][cc + 2] = v.z; w2S[r][cc + 3] = v.w;
        }
        __syncthreads();
        if (t < 270) {
            for (int u = 0; u < 256; ++u) {
                float p = hiS[u] + hjS[j][u] + b1S[u];
                p = p > 0.0f ? p : 0.0f;
                acc += p * w2S[c][u];
            }
        }
    }
    if (t < 270)
        out[((long)(b * 15 + i) * 15 + j) * 18 + c] = acc + b2[c];
}

// ---------------- energy stages 1+2 fused: gfeat recomputed per block (LDS)
__global__ __launch_bounds__(256) void energy12_k(
    const float* __restrict__ enr, const int* __restrict__ nodes,
    const float* __restrict__ Wh1, const float* __restrict__ bh1,
    const float* __restrict__ Wh2, float* __restrict__ hidr)
{
    const int b  = blockIdx.y;
    const int u0 = blockIdx.x * 16;
    const int t = threadIdx.x;
    __shared__ float gf[1024];

    int cnt = 0;
#pragma unroll
    for (int n = 0; n < 15; ++n) cnt += (nodes[b * 15 + n] != -1) ? 1 : 0;
    const float inv_valid = 1.0f / fmaxf((float)cnt, 1.0f);
    for (int e = t; e < 1024; e += 256) {
        float s = 0.0f;
#pragma unroll
        for (int n = 0; n < 15; ++n) {
            const bool ok = nodes[b * 15 + n] != -1;
            s += ok ? enr[(long)(b * 15 + n) * 1024 + e] : 0.0f;
        }
        gf[e] = s * inv_valid;
    }
    __syncthreads();

    const int wave = t >> 6, lane = t & 63;
#pragma unroll
    for (int r = 0; r < 4; ++r) {
        const int u = u0 + wave * 4 + r;
        float s = 0.0f;
#pragma unroll
        for (int e0 = 0; e0 < 1024; e0 += 64)
            s += gf[e0 + lane] * Wh1[(long)u * 1024 + e0 + lane];
#pragma unroll
        for (int o = 32; o; o >>= 1) s += __shfl_xor(s, o);
        if (lane == 0)
            hidr[b * 256 + u] = fmaxf(s + bh1[u], 0.0f) * Wh2[u];
    }
}

// ---------------- energy stage 3
__global__ __launch_bounds__(256) void energy3_k(
    const float* __restrict__ hidr, const float* __restrict__ bh2,
    float* __restrict__ out)
{
    const int b = blockIdx.x;
    const int t = threadIdx.x;
    __shared__ float red[4];
    float v = hidr[b * 256 + t];
#pragma unroll
    for (int o = 32; o; o >>= 1) v += __shfl_xor(v, o);
    if ((t & 63) == 0) red[t >> 6] = v;
    __syncthreads();
    if (t == 0) out[129600 + b] = red[0] + red[1] + red[2] + red[3] + bh2[0];
}

// ---------------------------------------------------------------------------
extern "C" void kernel_launch(void* const* d_in, const int* in_sizes, int n_in,
                              void* d_out, int out_size, void* d_ws, size_t ws_size,
                              hipStream_t stream)
{
    const float* visual = (const float*)d_in[0];
    const int*   nodes  = (const int*)  d_in[1];
    const float* bboxes = (const float*)d_in[2];
    const float* emb    = (const float*)d_in[3];
    const float* Wb     = (const float*)d_in[4];
    const float* bb     = (const float*)d_in[5];
    const float* Wq     = (const float*)d_in[6];
    const float* bq     = (const float*)d_in[7];
    const float* Wk     = (const float*)d_in[8];
    /* bk (d_in[9]) cancels in softmax */
    const float* Wv     = (const float*)d_in[10];
    const float* bv     = (const float*)d_in[11];
    const float* Wo     = (const float*)d_in[12];
    const float* bo     = (const float*)d_in[13];
    const float* W1     = (const float*)d_in[14];
    const float* b1     = (const float*)d_in[15];
    const float* W2     = (const float*)d_in[16];
    const float* b2     = (const float*)d_in[17];
    const float* Wh1    = (const float*)d_in[18];
    const float* bh1    = (const float*)d_in[19];
    const float* Wh2    = (const float*)d_in[20];
    const float* bh2    = (const float*)d_in[21];

    float* out = (float*)d_out;
    float* ws  = (float*)d_ws;

    // workspace layout (offsets in fp32 words)
    unsigned short* query_bf = (unsigned short*)(ws);            // 512x1024 bf16
    unsigned short* q_bf     = (unsigned short*)(ws + 131072);   // 512x1024 bf16
    float* scores = ws + 262144;              // 32*120*1024 f32
    unsigned short* ctxf_bf  = (unsigned short*)(ws + 4194304);  // 32*120*1024 bf16
    unsigned short* ctx_bf   = (unsigned short*)(ws + 6160384);  // 512x1024 bf16
    float* enr    = ws + 6422528;             // 480*1024 f32
    unsigned short* enr_bf   = (unsigned short*)(ws + 6914048);  // 512x1024 bf16
    float* hh     = ws + 7176192;             // 480*1024 f32 (hi|hj)
    unsigned short* Wq_bf  = (unsigned short*)(ws + 7667712);    // 1024x1024 bf16
    unsigned short* Wo_bf  = (unsigned short*)(ws + 8192000);    // 1024x1024 bf16
    unsigned short* Wv_bf  = (unsigned short*)(ws + 8716288);    // 1024x1024 bf16
    unsigned short* W1r_bf = (unsigned short*)(ws + 9240576);    // 1024x1024 bf16
    unsigned short* WkT_bf = (unsigned short*)(ws + 9764864);    // 1024x1024 bf16
    unsigned short* qW_bf   = (unsigned short*)(ws + 10289152);  // 32*128*1024 bf16
    unsigned short* attn_bf = (unsigned short*)(ws + 12386304);  // 32*128*1024 bf16
    unsigned short* v_bf    = (unsigned short*)(ws + 14483456);  // 32*1024*1024 bf16
    unsigned short* v_bfT   = (unsigned short*)(ws + 31260672);  // 32*1024*1024 bf16
    float* hidr   = ws + 48070656;            // 32*256

    const float inv_sqrt_hd = 0.08838834764831845f;  // 1/sqrt(128)
    const float* v_f = visual + 3 * 1048576;         // frame T-1; batch stride 4*1048576

    // 1) all input conversions: one uber kernel + the big v-convert
    uber_cvt_k<<<4832, 256, 0, stream>>>(
        nodes, bboxes, emb, Wb, bb, query_bf,
        Wq, Wo, Wv, W1, Wk, Wq_bf, Wo_bf, Wv_bf, W1r_bf, WkT_bf);
    cvt_k<<<dim3(16, 16, 32), 256, 0, stream>>>(v_f, v_bf, v_bfT);

    // 2) q_bf = query_bf @ Wq_bf^T + bq   (MFMA, bf16-only out)
    pgemm_k<2><<<dim3(16, 8), 256, 0, stream>>>(
        query_bf, Wq_bf, bq, nullptr, q_bf, 480, 1024, 1024, 1024, 1024);

    // 3) qW_bf = (q_bf @ WkT_bf^T) * inv_sqrt_hd   (MFMA, batch (b,h))
    qw_k<<<dim3(4, 256), 256, 0, stream>>>(q_bf, WkT_bf, qW_bf, inv_sqrt_hd);

    // 4) scores[b] = qW_bf[b] @ v_bf[b]^T   (MFMA, M=120 pad 128)
    bfgemm_k<false><<<dim3(8, 2, 32), 256, 0, stream>>>(
        qW_bf, v_bf, scores, 120, 131072, 1048576, 122880);

    // 5) softmax over l -> bf16 attn
    softmax_k<<<3840, 256, 0, stream>>>(scores, attn_bf);

    // 6) ctxf_bf[b] = attn[b] @ v_bfT[b]^T  (MFMA, bf16 out)
    bfgemm_k<true><<<dim3(8, 2, 32), 256, 0, stream>>>(
        attn_bf, v_bfT, ctxf_bf, 120, 131072, 1048576, 122880);

    // 7) ctx_bf = ctxf_bf @ Wv^T + bv      (MFMA, batch (b,h))
    ctx_k<<<256, 256, 0, stream>>>(ctxf_bf, Wv_bf, bv, ctx_bf);

    // 8) enr = ctx_bf @ Wo_bf^T + bo       (MFMA, dual out)
    pgemm_k<1><<<dim3(16, 8), 256, 0, stream>>>(
        ctx_bf, Wo_bf, bo, enr, enr_bf, 480, 1024, 1024, 1024, 1024);

    // 9) hh = enr_bf @ W1r_bf^T            (MFMA; cols 0..511 hi, 512..1023 hj)
    pgemm_k<0><<<dim3(16, 8), 256, 0, stream>>>(
        enr_bf, W1r_bf, nullptr, hh, nullptr, 480, 1024, 1024, 1024, 1024);

    // 10) edge logits -> out[0 .. 129600)   (b1 applied inside)
    edge_k<<<dim3(32, 15), 320, 0, stream>>>(hh, b1, W2, b2, out);

    // 11) energy -> out[129600 .. 129632)
    energy12_k<<<dim3(16, 32), 256, 0, stream>>>(enr, nodes, Wh1, bh1, Wh2, hidr);
    energy3_k<<<32, 256, 0, stream>>>(hidr, bh2, out);
}

// Round 13
// 214.884 us; speedup vs baseline: 3.0656x; 1.1097x over previous
//
#include <hip/hip_runtime.h>

// ---------------------------------------------------------------------------
// RelationalTransformer: B=32 T=4 L=1024 D=1024 H=8 Hd=128 N=15
// out = edge_logits (32*15*15*18 = 129600) ++ energy (32)   [fp32]
//
// R13: (a) scores GEMM converts v_f fp32->bf16 on the fly (LDS bytes identical
// to reading v_bf -> bit-exact); v_bf buffer eliminated; cvt reduced to
// transpose-only, launched after scores for L3 warmth. (b) edge+energy12
// fused into tail_k. 13 -> 12 dispatches.
// ---------------------------------------------------------------------------

typedef __attribute__((ext_vector_type(8))) short bf16x8;   // 8 bf16 in 4 VGPRs
typedef __attribute__((ext_vector_type(4))) float f32x4;

__device__ __forceinline__ unsigned short f2bf(float f) {   // RNE float->bf16
    unsigned int u = __float_as_uint(f);
    u = u + 0x7FFFu + ((u >> 16) & 1u);
    return (unsigned short)(u >> 16);
}

// async global->LDS, 16B per lane, dest = wave-uniform base + lane*16
__device__ __forceinline__ void gload_lds16(const void* g, void* l) {
    __builtin_amdgcn_global_load_lds(
        (const __attribute__((address_space(1))) void*)g,
        (__attribute__((address_space(3))) void*)l,
        16, 0, 0);
}

// ---------------- PV bf16 MFMA GEMM (64x128 tile, 4 waves): C = A @ B^T
__global__ __launch_bounds__(256) void bfgemm_k(
    const unsigned short* __restrict__ A, const unsigned short* __restrict__ B,
    unsigned short* __restrict__ C, int M, long sA, long sB, long sC)
{
    const int b  = blockIdx.z;
    const int m0 = blockIdx.y * 64;
    const int n0 = blockIdx.x * 128;
    const unsigned short* Ab = A + b * sA;
    const unsigned short* Bb = B + b * sB;

    __shared__ __align__(16) unsigned short As[64 * 32];   // [m][k]
    __shared__ __align__(16) unsigned short Bs[128 * 32];  // [n][k]

    const int t    = threadIdx.x;
    const int lane = t & 63;
    const int w    = t >> 6;
    const int wm   = w >> 1, wn = w & 1;       // wave tile: 32 x 64

    f32x4 acc[2][4] = {};

    const int ar = t >> 2;              // staging row (0..63)
    const int ac = (t & 3) * 8;         // staging k-offset (bf16 elems)

    unsigned short* AsW  = As + w * 512;
    unsigned short* BsW0 = Bs + w * 512;
    unsigned short* BsW1 = Bs + 2048 + w * 512;
    const unsigned short* ga  = Ab + (long)(m0 + ar) * 1024 + ac;
    const unsigned short* gb0 = Bb + (long)(n0 + ar) * 1024 + ac;
    const unsigned short* gb1 = Bb + (long)(n0 + 64 + ar) * 1024 + ac;

    for (int k0 = 0; k0 < 1024; k0 += 32) {
        __syncthreads();
        gload_lds16(ga  + k0, AsW);
        gload_lds16(gb0 + k0, BsW0);
        gload_lds16(gb1 + k0, BsW1);
        __syncthreads();

        const int krow = (lane >> 4) * 8;
        bf16x8 af[2], bf[4];
#pragma unroll
        for (int fi = 0; fi < 2; ++fi)
            af[fi] = *(const bf16x8*)&As[(wm * 32 + fi * 16 + (lane & 15)) * 32 + krow];
#pragma unroll
        for (int fj = 0; fj < 4; ++fj)
            bf[fj] = *(const bf16x8*)&Bs[(wn * 64 + fj * 16 + (lane & 15)) * 32 + krow];
#pragma unroll
        for (int fi = 0; fi < 2; ++fi)
#pragma unroll
            for (int fj = 0; fj < 4; ++fj)
                acc[fi][fj] = __builtin_amdgcn_mfma_f32_16x16x32_bf16(
                    af[fi], bf[fj], acc[fi][fj], 0, 0, 0);
    }

    const int rbase = (lane >> 4) * 4;
    const int cn    = n0 + wn * 64 + (lane & 15);
#pragma unroll
    for (int fi = 0; fi < 2; ++fi) {
        const int mb = m0 + wm * 32 + fi * 16 + rbase;
#pragma unroll
        for (int r = 0; r < 4; ++r) {
            const int m = mb + r;
            if (m < M) {
#pragma unroll
                for (int fj = 0; fj < 4; ++fj)
                    C[b * sC + (long)m * 1024 + cn + fj * 16] = f2bf(acc[fi][fj][r]);
            }
        }
    }
}

// ---------------- scores GEMM: A bf16 (gload), B = v_f fp32 converted on the
// fly (reg-stage + RNE cvt -> LDS bytes identical to v1 reading v_bf).
__global__ __launch_bounds__(256) void sgemm_k(
    const unsigned short* __restrict__ A, const float* __restrict__ Bf,
    float* __restrict__ C, int M, long sA, long sB, long sC)
{
    const int b  = blockIdx.z;
    const int m0 = blockIdx.y * 64;
    const int n0 = blockIdx.x * 128;
    const unsigned short* Ab = A + b * sA;
    const float* Bb = Bf + b * sB;
    float* Cb = C + b * sC;

    __shared__ __align__(16) unsigned short As[64 * 32];
    __shared__ __align__(16) unsigned short Bs[128 * 32];

    const int t    = threadIdx.x;
    const int lane = t & 63;
    const int w    = t >> 6;
    const int wm   = w >> 1, wn = w & 1;

    f32x4 acc[2][4] = {};

    const int ar = t >> 2;
    const int ac = (t & 3) * 8;

    unsigned short* AsW = As + w * 512;
    const unsigned short* ga = Ab + (long)(m0 + ar) * 1024 + ac;
    const float* gb0 = Bb + (long)(n0 + ar) * 1024 + ac;
    const float* gb1 = Bb + (long)(n0 + 64 + ar) * 1024 + ac;

    for (int k0 = 0; k0 < 1024; k0 += 32) {
        float4 v0a = *(const float4*)(gb0 + k0);
        float4 v0b = *(const float4*)(gb0 + k0 + 4);
        float4 v1a = *(const float4*)(gb1 + k0);
        float4 v1b = *(const float4*)(gb1 + k0 + 4);
        __syncthreads();                     // prior-iter ds_reads done
        gload_lds16(ga + k0, AsW);
        ushort4 o;
        o.x = f2bf(v0a.x); o.y = f2bf(v0a.y); o.z = f2bf(v0a.z); o.w = f2bf(v0a.w);
        *(ushort4*)&Bs[t * 8] = o;
        o.x = f2bf(v0b.x); o.y = f2bf(v0b.y); o.z = f2bf(v0b.z); o.w = f2bf(v0b.w);
        *(ushort4*)&Bs[t * 8 + 4] = o;
        o.x = f2bf(v1a.x); o.y = f2bf(v1a.y); o.z = f2bf(v1a.z); o.w = f2bf(v1a.w);
        *(ushort4*)&Bs[2048 + t * 8] = o;
        o.x = f2bf(v1b.x); o.y = f2bf(v1b.y); o.z = f2bf(v1b.z); o.w = f2bf(v1b.w);
        *(ushort4*)&Bs[2048 + t * 8 + 4] = o;
        __syncthreads();                     // drains vmcnt+lgkm

        const int krow = (lane >> 4) * 8;
        bf16x8 af[2], bf[4];
#pragma unroll
        for (int fi = 0; fi < 2; ++fi)
            af[fi] = *(const bf16x8*)&As[(wm * 32 + fi * 16 + (lane & 15)) * 32 + krow];
#pragma unroll
        for (int fj = 0; fj < 4; ++fj)
            bf[fj] = *(const bf16x8*)&Bs[(wn * 64 + fj * 16 + (lane & 15)) * 32 + krow];
#pragma unroll
        for (int fi = 0; fi < 2; ++fi)
#pragma unroll
            for (int fj = 0; fj < 4; ++fj)
                acc[fi][fj] = __builtin_amdgcn_mfma_f32_16x16x32_bf16(
                    af[fi], bf[fj], acc[fi][fj], 0, 0, 0);
    }

    const int rbase = (lane >> 4) * 4;
    const int cn    = n0 + wn * 64 + (lane & 15);
#pragma unroll
    for (int fi = 0; fi < 2; ++fi) {
        const int mb = m0 + wm * 32 + fi * 16 + rbase;
#pragma unroll
        for (int r = 0; r < 4; ++r) {
            const int m = mb + r;
            if (m < M) {
#pragma unroll
                for (int fj = 0; fj < 4; ++fj)
                    Cb[(long)m * 1024 + cn + fj * 16] = acc[fi][fj][r];
            }
        }
    }
}

// ---------------- projection bf16 MFMA GEMM (64x64 tile, gload_lds staging)
template <int OM>   // 0 = f32 only, 1 = dual, 2 = bf16 only
__global__ __launch_bounds__(256) void pgemm_k(
    const unsigned short* __restrict__ A, const unsigned short* __restrict__ B,
    const float* __restrict__ bias, float* __restrict__ C,
    unsigned short* __restrict__ Cbf,
    int M, int K, int lda, int ldb, int ldc)
{
    const int m0 = blockIdx.y * 64;
    const int n0 = blockIdx.x * 64;

    __shared__ __align__(16) unsigned short As[64 * 32];
    __shared__ __align__(16) unsigned short Bs[64 * 32];

    const int t    = threadIdx.x;
    const int lane = t & 63;
    const int w    = t >> 6;
    const int wm   = w >> 1, wn = w & 1;
    const int lm   = lane & 15, lg = lane >> 4;

    const int ar = t >> 2;
    const int ac = (t & 3) * 8;

    f32x4 acc[2][2] = {};

    unsigned short* AsW = As + w * 512;
    unsigned short* BsW = Bs + w * 512;
    const unsigned short* ga = A + (long)(m0 + ar) * lda + ac;
    const unsigned short* gb = B + (long)(n0 + ar) * ldb + ac;

    for (int k0 = 0; k0 < K; k0 += 32) {
        __syncthreads();
        gload_lds16(ga + k0, AsW);
        gload_lds16(gb + k0, BsW);
        __syncthreads();

        const int krow = lg * 8 & 24;
        bf16x8 af[2], bf[2];
#pragma unroll
        for (int fi = 0; fi < 2; ++fi)
            af[fi] = *(const bf16x8*)&As[(wm * 32 + fi * 16 + lm) * 32 + krow];
#pragma unroll
        for (int fj = 0; fj < 2; ++fj)
            bf[fj] = *(const bf16x8*)&Bs[(wn * 32 + fj * 16 + lm) * 32 + krow];
#pragma unroll
        for (int fi = 0; fi < 2; ++fi)
#pragma unroll
            for (int fj = 0; fj < 2; ++fj)
                acc[fi][fj] = __builtin_amdgcn_mfma_f32_16x16x32_bf16(
                    af[fi], bf[fj], acc[fi][fj], 0, 0, 0);
    }

    const int rbase = lg * 4;
#pragma unroll
    for (int fi = 0; fi < 2; ++fi) {
        const int mb = m0 + wm * 32 + fi * 16 + rbase;
#pragma unroll
        for (int r = 0; r < 4; ++r) {
            const int m = mb + r;
            if (m < M) {
#pragma unroll
                for (int fj = 0; fj < 2; ++fj) {
                    const int n = n0 + wn * 32 + fj * 16 + lm;
                    float v = acc[fi][fj][r];
                    if (bias) v += bias[n];
                    if constexpr (OM != 2) C[(long)m * ldc + n] = v;
                    if constexpr (OM >= 1) Cbf[(long)m * ldc + n] = f2bf(v);
                }
            }
        }
    }
}

// ---------------- qW kernel (unchanged)
__global__ __launch_bounds__(256) void qw_k(
    const unsigned short* __restrict__ qbf, const unsigned short* __restrict__ WkT,
    unsigned short* __restrict__ qW, float scale)
{
    const int z = blockIdx.y;
    const int b = z >> 3, h = z & 7;
    const int w = threadIdx.x >> 6, lane = threadIdx.x & 63;
    const int lm = lane & 15, lg = lane >> 4;
    const int n0w = blockIdx.x * 256 + w * 64;

    const unsigned short* Ar = qbf + (long)(b * 15 + lm) * 1024 + h * 128 + lg * 8;
    const unsigned short* Br = WkT + (long)(n0w + lm) * 1024 + h * 128 + lg * 8;

    bf16x8 af[4];
#pragma unroll
    for (int ks = 0; ks < 4; ++ks) af[ks] = *(const bf16x8*)(Ar + ks * 32);

    f32x4 acc[4] = {};
#pragma unroll
    for (int fj = 0; fj < 4; ++fj) {
#pragma unroll
        for (int ks = 0; ks < 4; ++ks) {
            bf16x8 bf = *(const bf16x8*)(Br + (long)fj * 16 * 1024 + ks * 32);
            acc[fj] = __builtin_amdgcn_mfma_f32_16x16x32_bf16(af[ks], bf, acc[fj], 0, 0, 0);
        }
    }

#pragma unroll
    for (int r = 0; r < 4; ++r) {
        const int m = lg * 4 + r;
        if (m < 15) {
#pragma unroll
            for (int fj = 0; fj < 4; ++fj)
                qW[(long)b * 131072 + (long)(m * 8 + h) * 1024 + n0w + fj * 16 + lm]
                    = f2bf(acc[fj][r] * scale);
        }
    }
}

// ---------------- ctx kernel (unchanged)
__global__ __launch_bounds__(256) void ctx_k(
    const unsigned short* __restrict__ cf, const unsigned short* __restrict__ Wvb,
    const float* __restrict__ bv, unsigned short* __restrict__ ctx)
{
    const int z = blockIdx.x;
    const int b = z >> 3, h = z & 7;
    const int w = threadIdx.x >> 6, lane = threadIdx.x & 63;
    const int lm = lane & 15, lg = lane >> 4;

    const unsigned short* Ar = cf + (long)b * 122880 + (long)(lm * 8 + h) * 1024 + lg * 8;
    const unsigned short* Br = Wvb + (long)(h * 128 + w * 32 + lm) * 1024 + lg * 8;

    f32x4 acc[2] = {};
    for (int k0 = 0; k0 < 1024; k0 += 32) {
        bf16x8 af = *(const bf16x8*)(Ar + k0);
        bf16x8 b0 = *(const bf16x8*)(Br + k0);
        bf16x8 b1 = *(const bf16x8*)(Br + 16 * 1024 + k0);
        acc[0] = __builtin_amdgcn_mfma_f32_16x16x32_bf16(af, b0, acc[0], 0, 0, 0);
        acc[1] = __builtin_amdgcn_mfma_f32_16x16x32_bf16(af, b1, acc[1], 0, 0, 0);
    }

#pragma unroll
    for (int r = 0; r < 4; ++r) {
        const int m = lg * 4 + r;
        if (m < 15) {
#pragma unroll
            for (int fj = 0; fj < 2; ++fj) {
                const int gcol = h * 128 + w * 32 + fj * 16 + lm;
                ctx[(long)(b * 15 + m) * 1024 + gcol] = f2bf(acc[fj][r] + bv[gcol]);
            }
        }
    }
}

// ---------------- uber conversion kernel (unchanged)
__global__ __launch_bounds__(256) void uber_cvt_k(
    const int* __restrict__ nodes, const float* __restrict__ bboxes,
    const float* __restrict__ emb, const float* __restrict__ Wb,
    const float* __restrict__ bb, unsigned short* __restrict__ qbf,
    const float* __restrict__ Wq, const float* __restrict__ Wo,
    const float* __restrict__ Wv, const float* __restrict__ W1,
    const float* __restrict__ Wk,
    unsigned short* __restrict__ dWq, unsigned short* __restrict__ dWo,
    unsigned short* __restrict__ dWv, unsigned short* __restrict__ dW1r,
    unsigned short* __restrict__ dWkT)
{
    __shared__ unsigned short tile[64][72];
    const int bid = blockIdx.x;
    const int t = threadIdx.x;

    if (bid < 4096) {
        const int which = bid >> 10;
        const int i = (bid & 1023) * 256 + t;
        const float* s;
        unsigned short* d;
        if (which == 3) {
            const int flat = i * 4, n = flat >> 10, k = flat & 1023;
            s = (n < 512) ? W1 + (long)n * 2048 + k
                          : W1 + (long)(n - 512) * 2048 + 1024 + k;
            d = dW1r + flat;
        } else {
            s = (which == 0 ? Wq : which == 1 ? Wo : Wv) + (long)i * 4;
            d = (which == 0 ? dWq : which == 1 ? dWo : dWv) + (long)i * 4;
        }
        float4 v = *(const float4*)s;
        ushort4 o;
        o.x = f2bf(v.x); o.y = f2bf(v.y); o.z = f2bf(v.z); o.w = f2bf(v.w);
        *(ushort4*)d = o;
    } else if (bid < 4352) {
        const int tl = bid - 4096;
        const int d0 = (tl >> 4) * 64, e0 = (tl & 15) * 64;
        const int r0 = t >> 4, c0 = (t & 15) * 4;
#pragma unroll
        for (int rr = 0; rr < 4; ++rr) {
            const int r = r0 + rr * 16;
            float4 v = *(const float4*)&Wk[(long)(d0 + r) * 1024 + e0 + c0];
            tile[r][c0 + 0] = f2bf(v.x); tile[r][c0 + 1] = f2bf(v.y);
            tile[r][c0 + 2] = f2bf(v.z); tile[r][c0 + 3] = f2bf(v.w);
        }
        __syncthreads();
#pragma unroll
        for (int rr = 0; rr < 4; ++rr) {
            const int idx = rr * 256 + t;
            const int e = idx >> 4, c4 = (idx & 15) * 4;
            ushort4 o;
            o.x = tile[c4 + 0][e]; o.y = tile[c4 + 1][e];
            o.z = tile[c4 + 2][e]; o.w = tile[c4 + 3][e];
            *(ushort4*)&dWkT[(long)(e0 + e) * 1024 + d0 + c4] = o;
        }
    } else {
        const int blk = bid - 4352;
        const int node = nodes[blk];
        const int idx = node < 0 ? 0 : node;
        const float4 bx = *(const float4*)&bboxes[blk * 4];
        const float* er = emb + (long)idx * 1024;
        for (int d = t; d < 1024; d += 256) {
            const float4 w = *(const float4*)&Wb[d * 4];
            qbf[(long)blk * 1024 + d] = f2bf(
                er[d] + bb[d] + bx.x * w.x + bx.y * w.y + bx.z * w.z + bx.w * w.w);
        }
    }
}

// ---------------- transpose-only convert: v_bfT[b][e][l] = bf16(v_f[b][l][e])
__global__ __launch_bounds__(256) void cvtT_k(
    const float* __restrict__ vf, unsigned short* __restrict__ vbfT)
{
    const int b  = blockIdx.z;
    const int e0 = blockIdx.x * 64;
    const int l0 = blockIdx.y * 64;
    const float* src = vf + (long)b * 4194304;   // batch stride = T*L*D
    __shared__ unsigned short tile[64][72];
    const int t = threadIdx.x;
    const int r0 = t >> 4, c0 = (t & 15) * 4;
#pragma unroll
    for (int rr = 0; rr < 4; ++rr) {
        const int r = r0 + rr * 16;
        float4 v = *(const float4*)&src[(long)(l0 + r) * 1024 + e0 + c0];
        tile[r][c0 + 0] = f2bf(v.x); tile[r][c0 + 1] = f2bf(v.y);
        tile[r][c0 + 2] = f2bf(v.z); tile[r][c0 + 3] = f2bf(v.w);
    }
    __syncthreads();
#pragma unroll
    for (int rr = 0; rr < 4; ++rr) {
        const int idx = rr * 256 + t;
        const int e   = idx >> 4;
        const int c4  = (idx & 15) * 4;
        ushort4 o;
        o.x = tile[c4 + 0][e]; o.y = tile[c4 + 1][e];
        o.z = tile[c4 + 2][e]; o.w = tile[c4 + 3][e];
        *(ushort4*)&vbfT[(long)b * 1048576 + (long)(e0 + e) * 1024 + l0 + c4] = o;
    }
}

// ---------------- row softmax over 1024; fp32 in, bf16 out (padded 128 rows/b)
__global__ __launch_bounds__(256) void softmax_k(
    const float* __restrict__ sc, unsigned short* __restrict__ attn)
{
    __shared__ float red[4];
    const int blk = blockIdx.x;              // b*120 + r
    const int b = blk / 120, r = blk % 120;
    const float* p = sc + (long)blk * 1024;
    const int t = threadIdx.x;
    float4 v = *(const float4*)&p[t * 4];

    float m = fmaxf(fmaxf(v.x, v.y), fmaxf(v.z, v.w));
#pragma unroll
    for (int o = 32; o; o >>= 1) m = fmaxf(m, __shfl_xor(m, o));
    if ((t & 63) == 0) red[t >> 6] = m;
    __syncthreads();
    m = fmaxf(fmaxf(red[0], red[1]), fmaxf(red[2], red[3]));
    __syncthreads();

    v.x = __expf(v.x - m); v.y = __expf(v.y - m);
    v.z = __expf(v.z - m); v.w = __expf(v.w - m);
    float s = v.x + v.y + v.z + v.w;
#pragma unroll
    for (int o = 32; o; o >>= 1) s += __shfl_xor(s, o);
    if ((t & 63) == 0) red[t >> 6] = s;
    __syncthreads();
    s = red[0] + red[1] + red[2] + red[3];
    const float inv = 1.0f / s;
    ushort4 o;
    o.x = f2bf(v.x * inv); o.y = f2bf(v.y * inv);
    o.z = f2bf(v.z * inv); o.w = f2bf(v.w * inv);
    *(ushort4*)&attn[(long)(b * 128 + r) * 1024 + t * 4] = o;
}

// ---------------- tail kernel: blocks [0,480) = edge head; [480,992) = energy12
__global__ __launch_bounds__(320) void tail_k(
    const float* __restrict__ hh, const float* __restrict__ b1,
    const float* __restrict__ W2, const float* __restrict__ b2,
    const float* __restrict__ enr, const int* __restrict__ nodes,
    const float* __restrict__ Wh1, const float* __restrict__ bh1,
    const float* __restrict__ Wh2, float* __restrict__ hidr,
    float* __restrict__ out)
{
    __shared__ float sm[8993];   // edge: hiS|b1S|hjS[15][257]|w2S[18][257]; energy: gf[1024]
    const int bid = blockIdx.x;
    const int t = threadIdx.x;

    if (bid < 480) {             // ---- edge: b = bid/15, i = bid%15
        const int b = bid / 15, i = bid % 15;
        float* hiS = sm;
        float* b1S = sm + 256;
        float* hjS = sm + 512;           // [15][257]
        float* w2S = sm + 512 + 3855;    // [18][257]
        const int j = t / 18, c = t % 18;
        float acc = 0.0f;

        for (int u0 = 0; u0 < 512; u0 += 256) {
            __syncthreads();
            if (t < 64) {
                float4 v = *(const float4*)&hh[(long)(b * 15 + i) * 1024 + u0 + t * 4];
                hiS[t * 4 + 0] = v.x; hiS[t * 4 + 1] = v.y;
                hiS[t * 4 + 2] = v.z; hiS[t * 4 + 3] = v.w;
            } else if (t < 128) {
                const int tt = t - 64;
                float4 v = *(const float4*)&b1[u0 + tt * 4];
                b1S[tt * 4 + 0] = v.x; b1S[tt * 4 + 1] = v.y;
                b1S[tt * 4 + 2] = v.z; b1S[tt * 4 + 3] = v.w;
            }
            for (int x = t; x < 960; x += 320) {
                const int r = x >> 6, cc = (x & 63) * 4;
                float4 v = *(const float4*)&hh[(long)(b * 15 + r) * 1024 + 512 + u0 + cc];
                hjS[r * 257 + cc + 0] = v.x; hjS[r * 257 + cc + 1] = v.y;
                hjS[r * 257 + cc + 2] = v.z; hjS[r * 257 + cc + 3] = v.w;
            }
            for (int x = t; x < 1152; x += 320) {
                const int r = x >> 6, cc = (x & 63) * 4;
                float4 v = *(const float4*)&W2[(long)r * 512 + u0 + cc];
                w2S[r * 257 + cc + 0] = v.x; w2S[r * 257 + cc + 1] = v.y;
                w2S[r * 257 + cc + 2] = v.z; w2S[r * 257 + cc + 3] = v.w;
            }
            __syncthreads();
            if (t < 270) {
                for (int u = 0; u < 256; ++u) {
                    float p = hiS[u] + hjS[j * 257 + u] + b1S[u];
                    p = p > 0.0f ? p : 0.0f;
                    acc += p * w2S[c * 257 + u];
                }
            }
        }
        if (t < 270)
            out[((long)(bid) * 15 + j) * 18 + c] = acc + b2[c];
    } else {                     // ---- energy12: z in [0,512)
        const int z = bid - 480;
        const int u0 = (z & 15) * 16;
        const int b  = z >> 4;
        float* gf = sm;

        int cnt = 0;
#pragma unroll
        for (int n = 0; n < 15; ++n) cnt += (nodes[b * 15 + n] != -1) ? 1 : 0;
        const float inv_valid = 1.0f / fmaxf((float)cnt, 1.0f);
        if (t < 256) {
            for (int e = t; e < 1024; e += 256) {
                float s = 0.0f;
#pragma unroll
                for (int n = 0; n < 15; ++n) {
                    const bool ok = nodes[b * 15 + n] != -1;
                    s += ok ? enr[(long)(b * 15 + n) * 1024 + e] : 0.0f;
                }
                gf[e] = s * inv_valid;
            }
        }
        __syncthreads();
        if (t < 256) {
            const int wave = t >> 6, lane = t & 63;
#pragma unroll
            for (int r = 0; r < 4; ++r) {
                const int u = u0 + wave * 4 + r;
                float s = 0.0f;
#pragma unroll
                for (int e0 = 0; e0 < 1024; e0 += 64)
                    s += gf[e0 + lane] * Wh1[(long)u * 1024 + e0 + lane];
#pragma unroll
                for (int o = 32; o; o >>= 1) s += __shfl_xor(s, o);
                if (lane == 0)
                    hidr[b * 256 + u] = fmaxf(s + bh1[u], 0.0f) * Wh2[u];
            }
        }
    }
}

// ---------------- energy stage 3
__global__ __launch_bounds__(256) void energy3_k(
    const float* __restrict__ hidr, const float* __restrict__ bh2,
    float* __restrict__ out)
{
    const int b = blockIdx.x;
    const int t = threadIdx.x;
    __shared__ float red[4];
    float v = hidr[b * 256 + t];
#pragma unroll
    for (int o = 32; o; o >>= 1) v += __shfl_xor(v, o);
    if ((t & 63) == 0) red[t >> 6] = v;
    __syncthreads();
    if (t == 0) out[129600 + b] = red[0] + red[1] + red[2] + red[3] + bh2[0];
}

// ---------------------------------------------------------------------------
extern "C" void kernel_launch(void* const* d_in, const int* in_sizes, int n_in,
                              void* d_out, int out_size, void* d_ws, size_t ws_size,
                              hipStream_t stream)
{
    const float* visual = (const float*)d_in[0];
    const int*   nodes  = (const int*)  d_in[1];
    const float* bboxes = (const float*)d_in[2];
    const float* emb    = (const float*)d_in[3];
    const float* Wb     = (const float*)d_in[4];
    const float* bb     = (const float*)d_in[5];
    const float* Wq     = (const float*)d_in[6];
    const float* bq     = (const float*)d_in[7];
    const float* Wk     = (const float*)d_in[8];
    /* bk (d_in[9]) cancels in softmax */
    const float* Wv     = (const float*)d_in[10];
    const float* bv     = (const float*)d_in[11];
    const float* Wo     = (const float*)d_in[12];
    const float* bo     = (const float*)d_in[13];
    const float* W1     = (const float*)d_in[14];
    const float* b1     = (const float*)d_in[15];
    const float* W2     = (const float*)d_in[16];
    const float* b2     = (const float*)d_in[17];
    const float* Wh1    = (const float*)d_in[18];
    const float* bh1    = (const float*)d_in[19];
    const float* Wh2    = (const float*)d_in[20];
    const float* bh2    = (const float*)d_in[21];

    float* out = (float*)d_out;
    float* ws  = (float*)d_ws;

    // workspace layout (offsets in fp32 words)
    unsigned short* query_bf = (unsigned short*)(ws);            // 512x1024 bf16
    unsigned short* q_bf     = (unsigned short*)(ws + 131072);   // 512x1024 bf16
    float* scores = ws + 262144;              // 32*120*1024 f32 (pad rows 128/b)
    unsigned short* ctxf_bf  = (unsigned short*)(ws + 4194304);  // 32*120*1024 bf16
    unsigned short* ctx_bf   = (unsigned short*)(ws + 6160384);  // 512x1024 bf16
    float* enr    = ws + 6422528;             // 480*1024 f32
    unsigned short* enr_bf   = (unsigned short*)(ws + 6914048);  // 512x1024 bf16
    float* hh     = ws + 7176192;             // 480*1024 f32 (hi|hj)
    unsigned short* Wq_bf  = (unsigned short*)(ws + 7667712);    // 1024x1024 bf16
    unsigned short* Wo_bf  = (unsigned short*)(ws + 8192000);    // 1024x1024 bf16
    unsigned short* Wv_bf  = (unsigned short*)(ws + 8716288);    // 1024x1024 bf16
    unsigned short* W1r_bf = (unsigned short*)(ws + 9240576);    // 1024x1024 bf16
    unsigned short* WkT_bf = (unsigned short*)(ws + 9764864);    // 1024x1024 bf16
    unsigned short* qW_bf   = (unsigned short*)(ws + 10289152);  // 32*128*1024 bf16
    unsigned short* attn_bf = (unsigned short*)(ws + 12386304);  // 32*128*1024 bf16
    unsigned short* v_bfT   = (unsigned short*)(ws + 31260672);  // 32*1024*1024 bf16
    float* hidr   = ws + 48070656;            // 32*256

    const float inv_sqrt_hd = 0.08838834764831845f;  // 1/sqrt(128)
    const float* v_f = visual + 3 * 1048576;         // frame T-1; batch stride 4*1048576

    // 1) weight/query conversions
    uber_cvt_k<<<4832, 256, 0, stream>>>(
        nodes, bboxes, emb, Wb, bb, query_bf,
        Wq, Wo, Wv, W1, Wk, Wq_bf, Wo_bf, Wv_bf, W1r_bf, WkT_bf);

    // 2) q_bf = query_bf @ Wq_bf^T + bq   (MFMA, bf16-only out)
    pgemm_k<2><<<dim3(16, 8), 256, 0, stream>>>(
        query_bf, Wq_bf, bq, nullptr, q_bf, 480, 1024, 1024, 1024, 1024);

    // 3) qW_bf = (q_bf @ WkT_bf^T) * inv_sqrt_hd   (MFMA, batch (b,h))
    qw_k<<<dim3(4, 256), 256, 0, stream>>>(q_bf, WkT_bf, qW_bf, inv_sqrt_hd);

    // 4) scores[b] = qW_bf[b] @ bf16(v_f[b])^T   (on-the-fly B convert)
    sgemm_k<<<dim3(8, 2, 32), 256, 0, stream>>>(
        qW_bf, v_f, scores, 120, 131072, 4194304, 122880);

    // 4b) v_bfT transpose-convert (after scores: v_f now L3-warm)
    cvtT_k<<<dim3(16, 16, 32), 256, 0, stream>>>(v_f, v_bfT);

    // 5) softmax over l -> bf16 attn
    softmax_k<<<3840, 256, 0, stream>>>(scores, attn_bf);

    // 6) ctxf_bf[b] = attn[b] @ v_bfT[b]^T  (MFMA, bf16 out)
    bfgemm_k<<<dim3(8, 2, 32), 256, 0, stream>>>(
        attn_bf, v_bfT, ctxf_bf, 120, 131072, 1048576, 122880);

    // 7) ctx_bf = ctxf_bf @ Wv^T + bv      (MFMA, batch (b,h))
    ctx_k<<<256, 256, 0, stream>>>(ctxf_bf, Wv_bf, bv, ctx_bf);

    // 8) enr = ctx_bf @ Wo_bf^T + bo       (MFMA, dual out)
    pgemm_k<1><<<dim3(16, 8), 256, 0, stream>>>(
        ctx_bf, Wo_bf, bo, enr, enr_bf, 480, 1024, 1024, 1024, 1024);

    // 9) hh = enr_bf @ W1r_bf^T            (MFMA; cols 0..511 hi, 512..1023 hj)
    pgemm_k<0><<<dim3(16, 8), 256, 0, stream>>>(
        enr_bf, W1r_bf, nullptr, hh, nullptr, 480, 1024, 1024, 1024, 1024);

    // 10) edge + energy12 fused -> out[0..129600) and hidr
    tail_k<<<992, 320, 0, stream>>>(
        hh, b1, W2, b2, enr, nodes, Wh1, bh1, Wh2, hidr, out);

    // 11) energy -> out[129600 .. 129632)
    energy3_k<<<32, 256, 0, stream>>>(hidr, bh2, out);
}